// Round 15
// baseline (141.418 us; speedup 1.0000x reference)
//
#include <hip/hip_runtime.h>
#include <math.h>

#define E 256
#define KTOP 10
#define NY 8
#define NINF (-__builtin_huge_valf())

typedef __attribute__((ext_vector_type(4))) float f32x4;
typedef __attribute__((ext_vector_type(2))) long i64x2;

// ---------- helpers ----------
__device__ inline float wsum(float v) {
    v += __shfl_xor(v, 1, 64);
    v += __shfl_xor(v, 2, 64);
    v += __shfl_xor(v, 4, 64);
    v += __shfl_xor(v, 8, 64);
    v += __shfl_xor(v, 16, 64);
    v += __shfl_xor(v, 32, 64);
    return v;
}

__device__ inline float wmax(float v) {
    v = fmaxf(v, __shfl_xor(v, 1, 64));
    v = fmaxf(v, __shfl_xor(v, 2, 64));
    v = fmaxf(v, __shfl_xor(v, 4, 64));
    v = fmaxf(v, __shfl_xor(v, 8, 64));
    v = fmaxf(v, __shfl_xor(v, 16, 64));
    v = fmaxf(v, __shfl_xor(v, 32, 64));
    return v;
}

__device__ inline float dot4(float4 a, float4 b) {
    return a.x * b.x + a.y * b.y + a.z * b.z + a.w * b.w;
}

__device__ inline void atomicMaxF(float* addr, float v) {
    atomicMax((unsigned int*)addr, __float_as_uint(v));  // non-negative floats
}

// f32 -> fp8 e4m3fn (OCP), RNE, saturating. Manual fallback (no API deps).
__device__ inline unsigned char f2fp8(float x) {
    unsigned u = __float_as_uint(x);
    unsigned s = (u >> 24) & 0x80u;
    int e = (int)((u >> 23) & 0xFF) - 127;
    unsigned m = u & 0x7FFFFFu;
    if (e < -9) return (unsigned char)s;                 // -> 0
    if (e > 8) return (unsigned char)(s | 0x7E);         // saturate to 448
    if (e >= -6) {                                       // normal
        unsigned mant = m >> 20;
        unsigned rest = m & 0xFFFFFu;
        if (rest > 0x80000u || (rest == 0x80000u && (mant & 1))) mant++;
        unsigned v = (((unsigned)(e + 7)) << 3) + mant;  // carry into exp is fine
        if (v > 0x7Eu) v = 0x7Eu;
        return (unsigned char)(s | v);
    }
    int rs = 20 + (-6 - e);                              // subnormal, shift 1..3
    unsigned full = 0x800000u | m;
    unsigned mant = full >> rs;
    unsigned rem = full & ((1u << rs) - 1u);
    unsigned half = 1u << (rs - 1);
    if (rem > half || (rem == half && (mant & 1))) mant++;
    if (mant >= 8u) return (unsigned char)(s | 0x08u);
    return (unsigned char)(s | mant);
}

#if defined(__has_builtin)
#if __has_builtin(__builtin_amdgcn_cvt_pk_fp8_f32)
#define HAVE_HW_FP8 1
#endif
#endif

// 4x f32 -> packed fp8 dword (bytes [a,b,c,d] little-endian)
__device__ inline unsigned pack_fp8x4(float a, float b, float c, float d) {
#ifdef HAVE_HW_FP8
    int lo = __builtin_amdgcn_cvt_pk_fp8_f32(a, b, 0, false);
    return (unsigned)__builtin_amdgcn_cvt_pk_fp8_f32(c, d, lo, true);
#else
    return (unsigned)f2fp8(a) | ((unsigned)f2fp8(b) << 8) |
           ((unsigned)f2fp8(c) << 16) | ((unsigned)f2fp8(d) << 24);
#endif
}

// fp8 tile layout (4096B per 16-col tile), [g][lk][col] order:
// byte(e, col) = (e>>6)*1024 + ((e&31)>>3)*256 + col*16 + ((e>>5)&1)*8 + (e&7)
// => MFMA fragment read for lane (col=lr, lk) at g*1024 + lane*16 (contiguous).
__device__ inline int tile_off(int e0, int col) {
    return ((e0 >> 6) << 10) + (((e0 & 31) >> 3) << 8) + (col << 4) +
           (((e0 >> 5) & 1) << 3) + (e0 & 7);
}

// ---------- kernels ----------
// hop_rel rows + all small norms (rel/arg1/arg2 + hop_rel norms)
__global__ void k_hoprel(const float* __restrict__ rel, const float* __restrict__ arg1,
                         const float* __restrict__ arg2, const float* __restrict__ W,
                         const float* __restrict__ bias, float* __restrict__ hr,
                         float* __restrict__ nhr, float* __restrict__ nrel,
                         float* __restrict__ na1, float* __restrict__ na2, int B) {
    int b = blockIdx.x, rh = blockIdx.y;
    int j = threadIdx.x;  // 0..255
    __shared__ float relS[E];
    __shared__ float red[4];
    __shared__ float red2[4];
    relS[j] = rel[b * E + j];
    __syncthreads();
    const float* Wp = W + (size_t)rh * E * E;
    float acc = bias[rh * E + j];
#pragma unroll 8
    for (int e = 0; e < E; ++e) acc = fmaf(relS[e], Wp[e * E + j], acc);
    hr[((size_t)rh * B + b) * E + j] = acc;
    float s = wsum(acc * acc);
    int wave = j >> 6;
    if ((j & 63) == 0) red[wave] = s;
    float x = 0.f;
    if (rh == 0) x = relS[j];
    else if (rh == 1) x = arg1[b * E + j];
    else if (rh == 2) x = arg2[b * E + j];
    float s2 = wsum(x * x);
    if ((j & 63) == 0) red2[wave] = s2;
    __syncthreads();
    if (j == 0) {
        nhr[rh * B + b] = red[0] + red[1] + red[2] + red[3];
        if (rh < 3) {
            float nv = red2[0] + red2[1] + red2[2] + red2[3];
            (rh == 0 ? nrel : (rh == 1 ? na1 : na2))[b] = nv;
        }
    }
}

// ent: norms + fp8 row-major (hop2 gather) + fp8 tiled (hop1 A-side)
__global__ void k_prep_ent(const float* __restrict__ ent, unsigned char* __restrict__ entb,
                           unsigned char* __restrict__ entt, float* __restrict__ ne_,
                           int BN, int N) {
    int row = blockIdx.x * 4 + (threadIdx.x >> 6);
    if (row >= BN) return;
    int lane = threadIdx.x & 63;
    float4 v = ((const float4*)(ent + (size_t)row * E))[lane];
    float s = wsum(dot4(v, v));
    if (lane == 0) ne_[row] = s;
    unsigned o = pack_fp8x4(v.x, v.y, v.z, v.w);
    ((unsigned*)(entb + (size_t)row * E))[lane] = o;
    int b = row / N, n = row % N;
    size_t tbase = ((size_t)b * (N >> 4) + (n >> 4)) * 4096;
    *(unsigned*)(entt + tbase + tile_off(lane * 4, n & 15)) = o;
}

// 16 facts per wave; lane = (fact g = lane>>2, chunk c = lane&3).
// Each lane serially accumulates a 64-element slice of 12 dot products;
// reduction is quad-only (xor1+xor2 = DPP, no LDS-pipe traffic).
// Each wave owns exactly one 4KB fp8 tile per array. Grid (F/64, B).
__global__ __launch_bounds__(256, 2) void k_fused(
    const float* __restrict__ rel, const float* __restrict__ arg1,
    const float* __restrict__ arg2, const float* __restrict__ frel,
    const float* __restrict__ fa1, const float* __restrict__ fa2,
    const int* __restrict__ nbf, const float* __restrict__ hr,
    const float* __restrict__ nhr, const float* __restrict__ nrel,
    const float* __restrict__ na1, const float* __restrict__ na2,
    float* __restrict__ lw1, float* __restrict__ lw2, float* __restrict__ s0log,
    float* __restrict__ nf1, float* __restrict__ nf2,
    unsigned char* __restrict__ fa1b, unsigned char* __restrict__ fa2b,
    int B, int F) {
    int b = blockIdx.y;
    int lane = threadIdx.x & 63, wave = threadIdx.x >> 6;
    int g = lane >> 2, c = lane & 3;
    int f0 = blockIdx.x * 64 + wave * 16;  // wave's 16-fact tile (16-aligned)
    int f = f0 + g;
    size_t bfg = (size_t)b * F + f;
    const float4* fr4 = (const float4*)(frel + bfg * E);
    const float4* f14 = (const float4*)(fa1 + bfg * E);
    const float4* f24 = (const float4*)(fa2 + bfg * E);
    const float4* q0 = (const float4*)(rel + (size_t)b * E);
    const float4* q1 = (const float4*)(arg1 + (size_t)b * E);
    const float4* q2 = (const float4*)(arg2 + (size_t)b * E);
    const float4* q3 = (const float4*)(hr + ((size_t)0 * B + b) * E);
    const float4* q4 = (const float4*)(hr + ((size_t)1 * B + b) * E);
    const float4* q5 = (const float4*)(hr + ((size_t)2 * B + b) * E);
    const float4* q6 = (const float4*)(hr + ((size_t)3 * B + b) * E);
    unsigned char* t1 = fa1b + ((size_t)b * (F >> 4) + (f0 >> 4)) * 4096;
    unsigned char* t2 = fa2b + ((size_t)b * (F >> 4) + (f0 >> 4)) * 4096;
    int base = c * 16;  // float4 index of this lane's 64-element slice

    float s_rel = 0.f, s_h00 = 0.f, s_h01 = 0.f, s_h10 = 0.f, s_h11 = 0.f;
    float s_nfr = 0.f, s_a1f1 = 0.f, s_a2f1 = 0.f, s_nf1 = 0.f;
    float s_a1f2 = 0.f, s_a2f2 = 0.f, s_nf2 = 0.f;
#pragma unroll
    for (int k = 0; k < 16; ++k) {
        float4 vr = fr4[base + k];
        float4 v1 = f14[base + k];
        float4 v2 = f24[base + k];
        float4 a0 = q0[base + k];
        float4 a1 = q1[base + k];
        float4 a2 = q2[base + k];
        float4 a3 = q3[base + k];
        float4 a4 = q4[base + k];
        float4 a5 = q5[base + k];
        float4 a6 = q6[base + k];
        s_rel  += dot4(vr, a0);
        s_h00  += dot4(vr, a3);
        s_h01  += dot4(vr, a4);
        s_h10  += dot4(vr, a5);
        s_h11  += dot4(vr, a6);
        s_nfr  += dot4(vr, vr);
        s_a1f1 += dot4(v1, a1);
        s_a2f1 += dot4(v1, a2);
        s_nf1  += dot4(v1, v1);
        s_a1f2 += dot4(v2, a1);
        s_a2f2 += dot4(v2, a2);
        s_nf2  += dot4(v2, v2);
        int e0 = c * 64 + k * 4;
        int off = tile_off(e0, g);
        *(unsigned*)(t1 + off) = pack_fp8x4(v1.x, v1.y, v1.z, v1.w);
        *(unsigned*)(t2 + off) = pack_fp8x4(v2.x, v2.y, v2.z, v2.w);
    }
    // quad reduction: xor1 + xor2 (DPP quad_perm — no LDS-pipe ops)
#define QR(s)                      \
    s += __shfl_xor(s, 1, 64);     \
    s += __shfl_xor(s, 2, 64);
    QR(s_rel) QR(s_h00) QR(s_h01) QR(s_h10) QR(s_h11) QR(s_nfr)
    QR(s_a1f1) QR(s_a2f1) QR(s_nf1) QR(s_a1f2) QR(s_a2f2) QR(s_nf2)
#undef QR
    if (c == 0) {
        bool msk = (f < nbf[b]);
        float rrel  = fmaxf(nrel[b] + s_nfr - 2.f * s_rel, 0.f);
        float rh00  = fmaxf(nhr[0 * B + b] + s_nfr - 2.f * s_h00, 0.f);
        float rh01  = fmaxf(nhr[1 * B + b] + s_nfr - 2.f * s_h01, 0.f);
        float rh10  = fmaxf(nhr[2 * B + b] + s_nfr - 2.f * s_h10, 0.f);
        float rh11  = fmaxf(nhr[3 * B + b] + s_nfr - 2.f * s_h11, 0.f);
        float ra1f1 = fmaxf(na1[b] + s_nf1 - 2.f * s_a1f1, 0.f);
        float ra2f1 = fmaxf(na2[b] + s_nf1 - 2.f * s_a2f1, 0.f);
        float ra1f2 = fmaxf(na1[b] + s_nf2 - 2.f * s_a1f2, 0.f);
        float ra2f2 = fmaxf(na2[b] + s_nf2 - 2.f * s_a2f2, 0.f);
        nf1[bfg] = s_nf1;
        nf2[bfg] = s_nf2;
        lw1[bfg]                 = msk ? -0.5f * (rh00 + ra1f1) : NINF;
        lw1[(size_t)B * F + bfg] = msk ? -0.5f * (rh10 + ra1f2) : NINF;
        lw2[bfg]                 = msk ? -0.5f * (rh01 + ra2f2) : NINF;
        lw2[(size_t)B * F + bfg] = msk ? -0.5f * (rh11 + ra2f1) : NINF;
        s0log[bfg] = msk ? -0.5f * (rrel + ra1f1 + ra2f2) : NINF;
    }
}

// out[b] = exp(max_f s0log[b][f])
__global__ void k_s0red(const float* __restrict__ s0log, float* __restrict__ out,
                        int B, int F) {
    int b = blockIdx.x;
    int tid = threadIdx.x, lane = tid & 63, wave = tid >> 6;
    float m = NINF;
    for (int f = tid; f < F; f += 256) m = fmaxf(m, s0log[(size_t)b * F + f]);
    m = wmax(m);
    __shared__ float red[4];
    if (lane == 0) red[wave] = m;
    __syncthreads();
    if (tid == 0) out[b] = expf(fmaxf(fmaxf(red[0], red[1]), fmaxf(red[2], red[3])));
}

// hop1: fp8 MFMA. A (32 rows/wave) in regs from tiled ent; B staged to LDS once
// per block, double-buffered, shared by 4 waves; conflict-free contiguous reads.
// Grid 2048: b(16) x r(2) x nb(8: 128-row) x fs(8: 256-col), XCD-swizzled.
__global__ __launch_bounds__(256, 4) void k_hop1m(
    const unsigned char* __restrict__ entt, const unsigned char* __restrict__ fa1b,
    const unsigned char* __restrict__ fa2b, const float* __restrict__ nf1,
    const float* __restrict__ nf2, const float* __restrict__ ne,
    const float* __restrict__ lw1, float* __restrict__ nsc_part, int B, int N, int F) {
    int L = blockIdx.x;
    int xcd = L & 7, s = L >> 3;
    int b = ((s >> 7) << 3) | xcd;  // batch-pair {xcd, xcd+8} per XCD
    int inner = s & 127;
    int r = inner >> 6, nb = (inner >> 3) & 7, fs = inner & 7;
    int BR = nb * 128;
    int F0 = fs * 256;
    const unsigned char* factb = (r == 0) ? fa2b : fa1b;
    const float* nfp = ((r == 0) ? nf2 : nf1) + (size_t)b * F;
    const float* w = lw1 + ((size_t)r * B + b) * F;
    const float* nep = ne + (size_t)b * N;

    __shared__ unsigned char bT[2][4096];

    int tid = threadIdx.x, lane = tid & 63, wave = tid >> 6;
    int lr = lane & 15, lk = lane >> 4;
    int row0 = BR + wave * 32;

    // A fragments: 2 m-frags x 8 kb; [g][lk][col] layout -> contiguous 16B loads
    const unsigned char* At = entt + (size_t)b * N * E;
    long areg[2][8];
#pragma unroll
    for (int m = 0; m < 2; ++m) {
        const unsigned char* p = At + (size_t)((row0 >> 4) + m) * 4096 + lk * 256 +
                                 lr * 16;
#pragma unroll
        for (int g = 0; g < 4; ++g) {
            i64x2 vv = *(const i64x2*)(p + g * 1024);
            areg[m][2 * g] = vv.x;
            areg[m][2 * g + 1] = vv.y;
        }
    }
    float nh[2][4];
#pragma unroll
    for (int m = 0; m < 2; ++m)
#pragma unroll
        for (int j = 0; j < 4; ++j)
            nh[m][j] = -0.5f * nep[row0 + m * 16 + lk * 4 + j];
    // preload per-tile lw / gf (statically indexed; t-loop fully unrolled)
    float lwa[16], gfa[16];
#pragma unroll
    for (int t = 0; t < 16; ++t) {
        int fcol = F0 + t * 16 + lr;
        lwa[t] = w[fcol];
        gfa[t] = fmaf(-0.5f, nfp[fcol], lwa[t]);
    }
    float vmax[2][4];
#pragma unroll
    for (int m = 0; m < 2; ++m)
#pragma unroll
        for (int j = 0; j < 4; ++j) vmax[m][j] = NINF;

    const unsigned char* Bt = factb + (size_t)b * F * E + (size_t)(F0 >> 4) * 4096;
#define STG(buf, t)                                                            \
    __builtin_amdgcn_global_load_lds(                                          \
        (const __attribute__((address_space(1))) void*)(Bt + (size_t)(t) * 4096 + \
                                                        wave * 1024 + lane * 16), \
        (__attribute__((address_space(3))) void*)&bT[buf][wave * 1024], 16, 0, 0)

    STG(0, 0);
    __syncthreads();
#pragma unroll
    for (int t = 0; t < 16; ++t) {
        int cur = t & 1;
        if (t < 15) STG(cur ^ 1, t + 1);
        long bfr[8];
#pragma unroll
        for (int g = 0; g < 4; ++g) {
            i64x2 vv = *(const i64x2*)&bT[cur][g * 1024 + lane * 16];
            bfr[2 * g] = vv.x;
            bfr[2 * g + 1] = vv.y;
        }
        f32x4 acc0 = {0.f, 0.f, 0.f, 0.f}, acc1 = {0.f, 0.f, 0.f, 0.f};
#pragma unroll
        for (int kb = 0; kb < 8; ++kb) {
            acc0 = __builtin_amdgcn_mfma_f32_16x16x32_fp8_fp8(areg[0][kb], bfr[kb],
                                                              acc0, 0, 0, 0);
            acc1 = __builtin_amdgcn_mfma_f32_16x16x32_fp8_fp8(areg[1][kb], bfr[kb],
                                                              acc1, 0, 0, 0);
        }
#pragma unroll
        for (int j = 0; j < 4; ++j) {
            vmax[0][j] = fmaxf(vmax[0][j], fminf(acc0[j] + gfa[t] + nh[0][j], lwa[t]));
            vmax[1][j] = fmaxf(vmax[1][j], fminf(acc1[j] + gfa[t] + nh[1][j], lwa[t]));
        }
        __syncthreads();
    }
#undef STG

    // reduce over the 16 lr lanes (different f, same rows); direct store
#pragma unroll
    for (int m = 0; m < 2; ++m)
#pragma unroll
        for (int j = 0; j < 4; ++j) {
            float v = vmax[m][j];
            v = fmaxf(v, __shfl_xor(v, 1, 64));
            v = fmaxf(v, __shfl_xor(v, 2, 64));
            v = fmaxf(v, __shfl_xor(v, 4, 64));
            v = fmaxf(v, __shfl_xor(v, 8, 64));
            if (lr == 0) {
                int row = row0 + m * 16 + lk * 4 + j;
                nsc_part[(size_t)fs * (2 * (size_t)B * N) +
                         ((size_t)r * B + b) * N + row] = v;
            }
        }
}

// top-10 per (r,b), 256 threads, register-resident, parallel NY-fold,
// jax.lax.top_k tie-break (lower index wins on equal value)
__global__ __launch_bounds__(256) void k_topk(const float* __restrict__ nsc_part,
                                              float* __restrict__ zval,
                                              int* __restrict__ zidx, int B, int N) {
    int b = blockIdx.x, r = blockIdx.y;
    int tid = threadIdx.x, lane = tid & 63, wave = tid >> 6;
    size_t rbN = ((size_t)r * B + b) * N;
    size_t ystr = 2 * (size_t)B * N;
    // fold NY partials: 8 independent float4 loads, one latency
    const float4* p0 = (const float4*)(nsc_part + rbN) + tid;
    float4 m = *p0;
#pragma unroll
    for (int y = 1; y < NY; ++y) {
        float4 t = *(const float4*)((const float*)p0 + (size_t)y * ystr);
        m.x = fmaxf(m.x, t.x); m.y = fmaxf(m.y, t.y);
        m.z = fmaxf(m.z, t.z); m.w = fmaxf(m.w, t.w);
    }
    float v0 = expf(m.x), v1 = expf(m.y), v2 = expf(m.z), v3 = expf(m.w);
    int base = tid * 4;
    __shared__ float rv[4];
    __shared__ int ri[4];
    for (int t = 0; t < KTOP; ++t) {
        // per-thread best of 4 (strict > keeps lowest index)
        float bv = v0; int bi = base;
        if (v1 > bv) { bv = v1; bi = base + 1; }
        if (v2 > bv) { bv = v2; bi = base + 2; }
        if (v3 > bv) { bv = v3; bi = base + 3; }
        // wave reduce
#pragma unroll
        for (int off = 32; off > 0; off >>= 1) {
            float ov = __shfl_xor(bv, off, 64);
            int oi = __shfl_xor(bi, off, 64);
            if (ov > bv || (ov == bv && oi < bi)) { bv = ov; bi = oi; }
        }
        if (lane == 0) { rv[wave] = bv; ri[wave] = bi; }
        __syncthreads();
        // cross-wave fold, computed redundantly (deterministic)
        float fb = rv[0]; int fi = ri[0];
#pragma unroll
        for (int wv = 1; wv < 4; ++wv) {
            float ov = rv[wv]; int oi = ri[wv];
            if (ov > fb || (ov == fb && oi < fi)) { fb = ov; fi = oi; }
        }
        if (tid == 0) {
            zval[((size_t)r * B + b) * KTOP + t] = fb;
            zidx[((size_t)r * B + b) * KTOP + t] = fi;
        }
        // owner clears its copy (static indexing via predicated writes)
        int off = fi - base;
        v0 = (off == 0) ? -2.f : v0;
        v1 = (off == 1) ? -2.f : v1;
        v2 = (off == 2) ? -2.f : v2;
        v3 = (off == 3) ? -2.f : v3;
        __syncthreads();
    }
}

// hop2 via fp8 MFMA: 10 gathered sources (A via LDS) vs tiled fact cols (B direct).
__global__ __launch_bounds__(256) void k_hop2m(
    const unsigned char* __restrict__ entb, const unsigned char* __restrict__ fa1b,
    const unsigned char* __restrict__ fa2b, const float* __restrict__ nf1,
    const float* __restrict__ nf2, const float* __restrict__ ne,
    const float* __restrict__ lw2, const int* __restrict__ zidx,
    float* __restrict__ h2part, int B, int N, int F) {
    int L = blockIdx.x;
    int xcd = L & 7, s = L >> 3;
    int b = ((s >> 4) << 3) | xcd;
    int inner = s & 15;
    int r = inner >> 3, c = inner & 7;
    const unsigned char* factb = (r == 0) ? fa1b : fa2b;
    const float* nfp = ((r == 0) ? nf1 : nf2) + (size_t)b * F;
    const float* w = lw2 + ((size_t)r * B + b) * F;
    int tid = threadIdx.x, lane = tid & 63, wave = tid >> 6;
    int lr = lane & 15, lk = lane >> 4;
    __shared__ unsigned char aLds[32 * 16 * 8];  // [kchunk32][row16][8B] = 4KB
    __shared__ float snrm[16];
    for (int ci = tid; ci < 512; ci += 256) {
        int row = ci & 15, kc = ci >> 4;
        long vv = 0;
        if (row < KTOP) {
            int idx = zidx[((size_t)r * B + b) * KTOP + row];
            vv = *(const long*)(entb + ((size_t)b * N + idx) * E + kc * 8);
        }
        *(long*)&aLds[(size_t)ci * 8] = vv;
    }
    if (tid < 16) {
        float nv = 0.f;
        if (tid < KTOP) {
            int idx = zidx[((size_t)r * B + b) * KTOP + tid];
            nv = ne[(size_t)b * N + idx];
        }
        snrm[tid] = nv;
    }
    __syncthreads();
    long afr[8];
#pragma unroll
    for (int kb = 0; kb < 8; ++kb)
        afr[kb] = *(const long*)&aLds[((kb * 4 + lk) * 16 + lr) * 8];
    float nhs[4];
#pragma unroll
    for (int j = 0; j < 4; ++j) nhs[j] = -0.5f * snrm[lk * 4 + j];
    int fbase = c * (F >> 3) + wave * (F >> 5);  // wave's 64 cols
    float vmax[4] = {NINF, NINF, NINF, NINF};
    const unsigned char* Bb = factb + (size_t)b * F * E;
#pragma unroll
    for (int n = 0; n < 4; ++n) {
        int fcol = fbase + n * 16;
        const unsigned char* p = Bb + (size_t)(fcol >> 4) * 4096 + lk * 256 + lr * 16;
        long bfr[8];
#pragma unroll
        for (int g = 0; g < 4; ++g) {
            i64x2 vv = *(const i64x2*)(p + g * 1024);
            bfr[2 * g] = vv.x;
            bfr[2 * g + 1] = vv.y;
        }
        f32x4 acc = {0.f, 0.f, 0.f, 0.f};
#pragma unroll
        for (int kb = 0; kb < 8; ++kb)
            acc = __builtin_amdgcn_mfma_f32_16x16x32_fp8_fp8(afr[kb], bfr[kb], acc,
                                                             0, 0, 0);
        float lwf = w[fcol + lr];
        float gf = fmaf(-0.5f, nfp[fcol + lr], lwf);
#pragma unroll
        for (int j = 0; j < 4; ++j)
            vmax[j] = fmaxf(vmax[j], fminf(acc[j] + gf + nhs[j], lwf));
    }
#pragma unroll
    for (int j = 0; j < 4; ++j) {
        float v = vmax[j];
        v = fmaxf(v, __shfl_xor(v, 1, 64));
        v = fmaxf(v, __shfl_xor(v, 2, 64));
        v = fmaxf(v, __shfl_xor(v, 4, 64));
        v = fmaxf(v, __shfl_xor(v, 8, 64));
        int sidx = lk * 4 + j;
        if (lr == 0 && sidx < KTOP)
            h2part[(((size_t)r * B + b) * KTOP + sidx) * 32 + c * 4 + wave] = v;
    }
}

// combine: out[b] = max(out[b], min(exp(max_c h2part), zval))
__global__ void k_hop2c(const float* __restrict__ h2part, const float* __restrict__ zval,
                        float* __restrict__ out, int B) {
    int i = blockIdx.x * 256 + threadIdx.x;
    int n = 2 * B * KTOP;
    if (i < n) {
        int b = (i / KTOP) % B;
        float m = NINF;
#pragma unroll
        for (int c2 = 0; c2 < 32; ++c2) m = fmaxf(m, h2part[(size_t)i * 32 + c2]);
        float sc = fminf(expf(m), zval[i]);
        atomicMaxF(&out[b], sc);
    }
}

// ---------- launcher ----------
extern "C" void kernel_launch(void* const* d_in, const int* in_sizes, int n_in,
                              void* d_out, int out_size, void* d_ws, size_t ws_size,
                              hipStream_t stream) {
    const float* rel = (const float*)d_in[0];
    const float* arg1 = (const float*)d_in[1];
    const float* arg2 = (const float*)d_in[2];
    const float* frel = (const float*)d_in[3];
    const float* fa1 = (const float*)d_in[4];
    const float* fa2 = (const float*)d_in[5];
    const int* nbf = (const int*)d_in[6];
    const float* ent = (const float*)d_in[7];
    const float* W = (const float*)d_in[9];
    const float* bias = (const float*)d_in[10];
    int B = in_sizes[0] / E;
    int F = in_sizes[3] / (B * E);
    int N = in_sizes[7] / (B * E);
    float* out = (float*)d_out;

    float* ws = (float*)d_ws;
    size_t o = 0;
    float* hr = ws + o;   o += (size_t)4 * B * E;
    float* nhr = ws + o;  o += (size_t)4 * B;
    float* nrel = ws + o; o += B;
    float* na1 = ws + o;  o += B;
    float* na2 = ws + o;  o += B * 2;  // keep 16B alignment
    float* nf1 = ws + o;  o += (size_t)B * F;
    float* nf2 = ws + o;  o += (size_t)B * F;
    float* ne_ = ws + o;  o += (size_t)B * N;
    float* lw1 = ws + o;  o += (size_t)2 * B * F;
    float* lw2 = ws + o;  o += (size_t)2 * B * F;
    float* zval = ws + o; o += (size_t)2 * B * KTOP;
    int* zidx = (int*)(ws + o); o += (size_t)2 * B * KTOP;
    float* s0log = ws + o; o += (size_t)B * F;
    float* h2part = ws + o; o += (size_t)2 * B * KTOP * 32;
    float* nsc_part = ws + o; o += (size_t)NY * 2 * B * N;
    unsigned char* fa1b = (unsigned char*)(ws + o); o += (size_t)B * F * E / 4;
    unsigned char* fa2b = (unsigned char*)(ws + o); o += (size_t)B * F * E / 4;
    unsigned char* entb = (unsigned char*)(ws + o); o += (size_t)B * N * E / 4;
    unsigned char* entt = (unsigned char*)(ws + o); o += (size_t)B * N * E / 4;

    k_hoprel<<<dim3(B, 4), dim3(E), 0, stream>>>(rel, arg1, arg2, W, bias, hr, nhr,
                                                 nrel, na1, na2, B);
    k_prep_ent<<<dim3((B * N + 3) / 4), dim3(256), 0, stream>>>(ent, entb, entt, ne_,
                                                                B * N, N);
    k_fused<<<dim3(F / 64, B), dim3(256), 0, stream>>>(
        rel, arg1, arg2, frel, fa1, fa2, nbf, hr, nhr, nrel, na1, na2, lw1, lw2,
        s0log, nf1, nf2, fa1b, fa2b, B, F);
    k_s0red<<<dim3(B), dim3(256), 0, stream>>>(s0log, out, B, F);
    k_hop1m<<<dim3(2048), dim3(256), 0, stream>>>(entt, fa1b, fa2b, nf1, nf2, ne_, lw1,
                                                  nsc_part, B, N, F);
    k_topk<<<dim3(B, 2), dim3(256), 0, stream>>>(nsc_part, zval, zidx, B, N);
    k_hop2m<<<dim3(256), dim3(256), 0, stream>>>(entb, fa1b, fa2b, nf1, nf2, ne_, lw2,
                                                 zidx, h2part, B, N, F);
    k_hop2c<<<dim3((2 * B * KTOP + 255) / 256), dim3(256), 0, stream>>>(h2part, zval,
                                                                        out, B);
}

// Round 16
// 99.940 us; speedup vs baseline: 1.4150x; 1.4150x over previous
//
#include <hip/hip_runtime.h>
#include <math.h>

#define E 256
#define KTOP 10
#define NY 8
#define NINF (-__builtin_huge_valf())

typedef __attribute__((ext_vector_type(4))) float f32x4;
typedef __attribute__((ext_vector_type(2))) long i64x2;

// ---------- helpers ----------
__device__ inline float wsum(float v) {
    v += __shfl_xor(v, 1, 64);
    v += __shfl_xor(v, 2, 64);
    v += __shfl_xor(v, 4, 64);
    v += __shfl_xor(v, 8, 64);
    v += __shfl_xor(v, 16, 64);
    v += __shfl_xor(v, 32, 64);
    return v;
}

__device__ inline float wmax(float v) {
    v = fmaxf(v, __shfl_xor(v, 1, 64));
    v = fmaxf(v, __shfl_xor(v, 2, 64));
    v = fmaxf(v, __shfl_xor(v, 4, 64));
    v = fmaxf(v, __shfl_xor(v, 8, 64));
    v = fmaxf(v, __shfl_xor(v, 16, 64));
    v = fmaxf(v, __shfl_xor(v, 32, 64));
    return v;
}

__device__ inline float dot4(float4 a, float4 b) {
    return a.x * b.x + a.y * b.y + a.z * b.z + a.w * b.w;
}

__device__ inline void atomicMaxF(float* addr, float v) {
    atomicMax((unsigned int*)addr, __float_as_uint(v));  // non-negative floats
}

// f32 -> fp8 e4m3fn (OCP), RNE, saturating. Manual fallback (no API deps).
__device__ inline unsigned char f2fp8(float x) {
    unsigned u = __float_as_uint(x);
    unsigned s = (u >> 24) & 0x80u;
    int e = (int)((u >> 23) & 0xFF) - 127;
    unsigned m = u & 0x7FFFFFu;
    if (e < -9) return (unsigned char)s;                 // -> 0
    if (e > 8) return (unsigned char)(s | 0x7E);         // saturate to 448
    if (e >= -6) {                                       // normal
        unsigned mant = m >> 20;
        unsigned rest = m & 0xFFFFFu;
        if (rest > 0x80000u || (rest == 0x80000u && (mant & 1))) mant++;
        unsigned v = (((unsigned)(e + 7)) << 3) + mant;  // carry into exp is fine
        if (v > 0x7Eu) v = 0x7Eu;
        return (unsigned char)(s | v);
    }
    int rs = 20 + (-6 - e);                              // subnormal, shift 1..3
    unsigned full = 0x800000u | m;
    unsigned mant = full >> rs;
    unsigned rem = full & ((1u << rs) - 1u);
    unsigned half = 1u << (rs - 1);
    if (rem > half || (rem == half && (mant & 1))) mant++;
    if (mant >= 8u) return (unsigned char)(s | 0x08u);
    return (unsigned char)(s | mant);
}

#if defined(__has_builtin)
#if __has_builtin(__builtin_amdgcn_cvt_pk_fp8_f32)
#define HAVE_HW_FP8 1
#endif
#endif

// 4x f32 -> packed fp8 dword (bytes [a,b,c,d] little-endian)
__device__ inline unsigned pack_fp8x4(float a, float b, float c, float d) {
#ifdef HAVE_HW_FP8
    int lo = __builtin_amdgcn_cvt_pk_fp8_f32(a, b, 0, false);
    return (unsigned)__builtin_amdgcn_cvt_pk_fp8_f32(c, d, lo, true);
#else
    return (unsigned)f2fp8(a) | ((unsigned)f2fp8(b) << 8) |
           ((unsigned)f2fp8(c) << 16) | ((unsigned)f2fp8(d) << 24);
#endif
}

// fp8 tile layout (4096B per 16-col tile), [g][lk][col] order:
// byte(e, col) = (e>>6)*1024 + ((e&31)>>3)*256 + col*16 + ((e>>5)&1)*8 + (e&7)
// => MFMA fragment read for lane (col=lr, lk) at g*1024 + lane*16 (contiguous).
__device__ inline int tile_off(int e0, int col) {
    return ((e0 >> 6) << 10) + (((e0 & 31) >> 3) << 8) + (col << 4) +
           (((e0 >> 5) & 1) << 3) + (e0 & 7);
}

// ---------- kernels ----------
// hop_rel rows only (norms now come from MFMA Q.Q diagonal)
__global__ void k_hoprel(const float* __restrict__ rel, const float* __restrict__ W,
                         const float* __restrict__ bias, float* __restrict__ hr,
                         int B) {
    int b = blockIdx.x, rh = blockIdx.y;
    int j = threadIdx.x;  // 0..255
    __shared__ float relS[E];
    relS[j] = rel[b * E + j];
    __syncthreads();
    const float* Wp = W + (size_t)rh * E * E;
    float acc = bias[rh * E + j];
#pragma unroll 8
    for (int e = 0; e < E; ++e) acc = fmaf(relS[e], Wp[e * E + j], acc);
    hr[((size_t)rh * B + b) * E + j] = acc;
}

// ent: norms + fp8 row-major (hop2 gather) + fp8 tiled (hop1 A-side)
__global__ void k_prep_ent(const float* __restrict__ ent, unsigned char* __restrict__ entb,
                           unsigned char* __restrict__ entt, float* __restrict__ ne_,
                           int BN, int N) {
    int row = blockIdx.x * 4 + (threadIdx.x >> 6);
    if (row >= BN) return;
    int lane = threadIdx.x & 63;
    float4 v = ((const float4*)(ent + (size_t)row * E))[lane];
    float s = wsum(dot4(v, v));
    if (lane == 0) ne_[row] = s;
    unsigned o = pack_fp8x4(v.x, v.y, v.z, v.w);
    ((unsigned*)(entb + (size_t)row * E))[lane] = o;
    int b = row / N, n = row % N;
    size_t tbase = ((size_t)b * (N >> 4) + (n >> 4)) * 4096;
    *(unsigned*)(entt + tbase + tile_off(lane * 4, n & 15)) = o;
}

// pure streaming cast: frel/fa1/fa2 -> fp8 tiled. Wave per row, no reductions.
__global__ __launch_bounds__(256) void k_cast(
    const float* __restrict__ frel, const float* __restrict__ fa1,
    const float* __restrict__ fa2, unsigned char* __restrict__ frb,
    unsigned char* __restrict__ fa1b, unsigned char* __restrict__ fa2b,
    int B, int F) {
    int row = blockIdx.x * 4 + (threadIdx.x >> 6);
    int lane = threadIdx.x & 63;
    int BF = B * F;
    if (row >= 3 * BF) return;
    int a = row / BF, rem = row - a * BF;
    int b = rem / F, f = rem - b * F;
    const float* src = (a == 0) ? frel : (a == 1) ? fa1 : fa2;
    unsigned char* dst = (a == 0) ? frb : (a == 1) ? fa1b : fa2b;
    float4 v = ((const float4*)(src + (size_t)rem * E))[lane];
    size_t tbase = ((size_t)b * (F >> 4) + (f >> 4)) * 4096;
    *(unsigned*)(dst + tbase + tile_off(lane * 4, f & 15)) =
        pack_fp8x4(v.x, v.y, v.z, v.w);
}

// per-b fp8 query tile: rows {rel, arg1, arg2, hr00, hr01, hr10, hr11}, rest 0
__global__ __launch_bounds__(64) void k_prep_q(
    const float* __restrict__ rel, const float* __restrict__ arg1,
    const float* __restrict__ arg2, const float* __restrict__ hr,
    unsigned char* __restrict__ qt, int B) {
    int b = blockIdx.x;
    int lane = threadIdx.x;
    unsigned char* t = qt + (size_t)b * 4096;
#define ROW(q, ptr)                                                       \
    {                                                                     \
        float4 v = ((const float4*)(ptr))[lane];                          \
        *(unsigned*)(t + tile_off(lane * 4, q)) =                         \
            pack_fp8x4(v.x, v.y, v.z, v.w);                               \
    }
    ROW(0, rel + (size_t)b * E)
    ROW(1, arg1 + (size_t)b * E)
    ROW(2, arg2 + (size_t)b * E)
    ROW(3, hr + ((size_t)0 * B + b) * E)
    ROW(4, hr + ((size_t)1 * B + b) * E)
    ROW(5, hr + ((size_t)2 * B + b) * E)
    ROW(6, hr + ((size_t)3 * B + b) * E)
#undef ROW
#pragma unroll
    for (int q = 7; q < 16; ++q)
        *(unsigned*)(t + tile_off(lane * 4, q)) = 0u;
}

// all query-fact dots + norms via fp8 MFMA; log-space weights + s0log + nf.
// Wave per 16-fact tile. Grid (F/64, B).
__global__ __launch_bounds__(256) void k_pair(
    const unsigned char* __restrict__ qt, const unsigned char* __restrict__ frb,
    const unsigned char* __restrict__ fa1b, const unsigned char* __restrict__ fa2b,
    const int* __restrict__ nbf, float* __restrict__ lw1, float* __restrict__ lw2,
    float* __restrict__ s0log, float* __restrict__ nf1, float* __restrict__ nf2,
    int B, int F) {
    int b = blockIdx.y;
    int lane = threadIdx.x & 63, wave = threadIdx.x >> 6;
    int ti = blockIdx.x * 4 + wave;  // 16-fact tile index
    int f0 = ti * 16;
    int lr = lane & 15, lk = lane >> 4;
    const unsigned char* qp = qt + (size_t)b * 4096 + lk * 256 + lr * 16;
    size_t tb = ((size_t)b * (F >> 4) + ti) * 4096;
    const unsigned char* frp = frb + tb + lk * 256 + lr * 16;
    const unsigned char* f1p = fa1b + tb + lk * 256 + lr * 16;
    const unsigned char* f2p = fa2b + tb + lk * 256 + lr * 16;
    long Q[8], FR[8], F1[8], F2[8];
#pragma unroll
    for (int g = 0; g < 4; ++g) {
        i64x2 a = *(const i64x2*)(qp + g * 1024);
        Q[2 * g] = a.x; Q[2 * g + 1] = a.y;
        i64x2 c = *(const i64x2*)(frp + g * 1024);
        FR[2 * g] = c.x; FR[2 * g + 1] = c.y;
        i64x2 d = *(const i64x2*)(f1p + g * 1024);
        F1[2 * g] = d.x; F1[2 * g + 1] = d.y;
        i64x2 e2 = *(const i64x2*)(f2p + g * 1024);
        F2[2 * g] = e2.x; F2[2 * g + 1] = e2.y;
    }
    f32x4 Dqq = {0.f, 0.f, 0.f, 0.f}, D1 = Dqq, D2 = Dqq, D3 = Dqq, D4 = Dqq,
          D5 = Dqq, D6 = Dqq;
#pragma unroll
    for (int kb = 0; kb < 8; ++kb) {
        Dqq = __builtin_amdgcn_mfma_f32_16x16x32_fp8_fp8(Q[kb], Q[kb], Dqq, 0, 0, 0);
        D1 = __builtin_amdgcn_mfma_f32_16x16x32_fp8_fp8(Q[kb], FR[kb], D1, 0, 0, 0);
        D2 = __builtin_amdgcn_mfma_f32_16x16x32_fp8_fp8(Q[kb], F1[kb], D2, 0, 0, 0);
        D3 = __builtin_amdgcn_mfma_f32_16x16x32_fp8_fp8(Q[kb], F2[kb], D3, 0, 0, 0);
        D4 = __builtin_amdgcn_mfma_f32_16x16x32_fp8_fp8(FR[kb], FR[kb], D4, 0, 0, 0);
        D5 = __builtin_amdgcn_mfma_f32_16x16x32_fp8_fp8(F1[kb], F1[kb], D5, 0, 0, 0);
        D6 = __builtin_amdgcn_mfma_f32_16x16x32_fp8_fp8(F2[kb], F2[kb], D6, 0, 0, 0);
    }
    // scatter needed values to wave-local LDS (no block barrier: same-wave order)
    __shared__ float vals[4][16][12];
    __shared__ float qn[4][8];
#pragma unroll
    for (int j = 0; j < 4; ++j) {
        int q = lk * 4 + j;
        if (q == 0) vals[wave][lr][0] = D1[j];   // rel . fr
        if (q == 3) vals[wave][lr][1] = D1[j];   // h00 . fr
        if (q == 4) vals[wave][lr][2] = D1[j];   // h01 . fr
        if (q == 5) vals[wave][lr][3] = D1[j];   // h10 . fr
        if (q == 6) vals[wave][lr][4] = D1[j];   // h11 . fr
        if (q == 1) { vals[wave][lr][5] = D2[j]; vals[wave][lr][7] = D3[j]; }
        if (q == 2) { vals[wave][lr][6] = D2[j]; vals[wave][lr][8] = D3[j]; }
        if (q == lr) {
            vals[wave][lr][9] = D4[j];   // |fr|^2
            vals[wave][lr][10] = D5[j];  // |f1|^2
            vals[wave][lr][11] = D6[j];  // |f2|^2
            if (q < 7) qn[wave][q] = Dqq[j];
        }
    }
    if (lane < 16) {
        int f = f0 + lane;
        size_t bf = (size_t)b * F + f;
        const float* vv = vals[wave][lane];
        float nfr = vv[9], n1 = vv[10], n2 = vv[11];
        bool msk = (f < nbf[b]);
        float rrel  = fmaxf(qn[wave][0] + nfr - 2.f * vv[0], 0.f);
        float rh00  = fmaxf(qn[wave][3] + nfr - 2.f * vv[1], 0.f);
        float rh01  = fmaxf(qn[wave][4] + nfr - 2.f * vv[2], 0.f);
        float rh10  = fmaxf(qn[wave][5] + nfr - 2.f * vv[3], 0.f);
        float rh11  = fmaxf(qn[wave][6] + nfr - 2.f * vv[4], 0.f);
        float ra1f1 = fmaxf(qn[wave][1] + n1 - 2.f * vv[5], 0.f);
        float ra2f1 = fmaxf(qn[wave][2] + n1 - 2.f * vv[6], 0.f);
        float ra1f2 = fmaxf(qn[wave][1] + n2 - 2.f * vv[7], 0.f);
        float ra2f2 = fmaxf(qn[wave][2] + n2 - 2.f * vv[8], 0.f);
        nf1[bf] = n1;
        nf2[bf] = n2;
        lw1[bf]                 = msk ? -0.5f * (rh00 + ra1f1) : NINF;
        lw1[(size_t)B * F + bf] = msk ? -0.5f * (rh10 + ra1f2) : NINF;
        lw2[bf]                 = msk ? -0.5f * (rh01 + ra2f2) : NINF;
        lw2[(size_t)B * F + bf] = msk ? -0.5f * (rh11 + ra2f1) : NINF;
        s0log[bf] = msk ? -0.5f * (rrel + ra1f1 + ra2f2) : NINF;
    }
}

// out[b] = exp(max_f s0log[b][f])
__global__ void k_s0red(const float* __restrict__ s0log, float* __restrict__ out,
                        int B, int F) {
    int b = blockIdx.x;
    int tid = threadIdx.x, lane = tid & 63, wave = tid >> 6;
    float m = NINF;
    for (int f = tid; f < F; f += 256) m = fmaxf(m, s0log[(size_t)b * F + f]);
    m = wmax(m);
    __shared__ float red[4];
    if (lane == 0) red[wave] = m;
    __syncthreads();
    if (tid == 0) out[b] = expf(fmaxf(fmaxf(red[0], red[1]), fmaxf(red[2], red[3])));
}

// hop1: fp8 MFMA. A (32 rows/wave) in regs from tiled ent; B staged to LDS once
// per block, double-buffered, shared by 4 waves; conflict-free contiguous reads.
// Grid 2048: b(16) x r(2) x nb(8: 128-row) x fs(8: 256-col), XCD-swizzled.
__global__ __launch_bounds__(256, 4) void k_hop1m(
    const unsigned char* __restrict__ entt, const unsigned char* __restrict__ fa1b,
    const unsigned char* __restrict__ fa2b, const float* __restrict__ nf1,
    const float* __restrict__ nf2, const float* __restrict__ ne,
    const float* __restrict__ lw1, float* __restrict__ nsc_part, int B, int N, int F) {
    int L = blockIdx.x;
    int xcd = L & 7, s = L >> 3;
    int b = ((s >> 7) << 3) | xcd;  // batch-pair {xcd, xcd+8} per XCD
    int inner = s & 127;
    int r = inner >> 6, nb = (inner >> 3) & 7, fs = inner & 7;
    int BR = nb * 128;
    int F0 = fs * 256;
    const unsigned char* factb = (r == 0) ? fa2b : fa1b;
    const float* nfp = ((r == 0) ? nf2 : nf1) + (size_t)b * F;
    const float* w = lw1 + ((size_t)r * B + b) * F;
    const float* nep = ne + (size_t)b * N;

    __shared__ unsigned char bT[2][4096];

    int tid = threadIdx.x, lane = tid & 63, wave = tid >> 6;
    int lr = lane & 15, lk = lane >> 4;
    int row0 = BR + wave * 32;

    // A fragments: 2 m-frags x 8 kb; [g][lk][col] layout -> contiguous 16B loads
    const unsigned char* At = entt + (size_t)b * N * E;
    long areg[2][8];
#pragma unroll
    for (int m = 0; m < 2; ++m) {
        const unsigned char* p = At + (size_t)((row0 >> 4) + m) * 4096 + lk * 256 +
                                 lr * 16;
#pragma unroll
        for (int g = 0; g < 4; ++g) {
            i64x2 vv = *(const i64x2*)(p + g * 1024);
            areg[m][2 * g] = vv.x;
            areg[m][2 * g + 1] = vv.y;
        }
    }
    float nh[2][4];
#pragma unroll
    for (int m = 0; m < 2; ++m)
#pragma unroll
        for (int j = 0; j < 4; ++j)
            nh[m][j] = -0.5f * nep[row0 + m * 16 + lk * 4 + j];
    // preload per-tile lw / gf (statically indexed; t-loop fully unrolled)
    float lwa[16], gfa[16];
#pragma unroll
    for (int t = 0; t < 16; ++t) {
        int fcol = F0 + t * 16 + lr;
        lwa[t] = w[fcol];
        gfa[t] = fmaf(-0.5f, nfp[fcol], lwa[t]);
    }
    float vmax[2][4];
#pragma unroll
    for (int m = 0; m < 2; ++m)
#pragma unroll
        for (int j = 0; j < 4; ++j) vmax[m][j] = NINF;

    const unsigned char* Bt = factb + (size_t)b * F * E + (size_t)(F0 >> 4) * 4096;
#define STG(buf, t)                                                            \
    __builtin_amdgcn_global_load_lds(                                          \
        (const __attribute__((address_space(1))) void*)(Bt + (size_t)(t) * 4096 + \
                                                        wave * 1024 + lane * 16), \
        (__attribute__((address_space(3))) void*)&bT[buf][wave * 1024], 16, 0, 0)

    STG(0, 0);
    __syncthreads();
#pragma unroll
    for (int t = 0; t < 16; ++t) {
        int cur = t & 1;
        if (t < 15) STG(cur ^ 1, t + 1);
        long bfr[8];
#pragma unroll
        for (int g = 0; g < 4; ++g) {
            i64x2 vv = *(const i64x2*)&bT[cur][g * 1024 + lane * 16];
            bfr[2 * g] = vv.x;
            bfr[2 * g + 1] = vv.y;
        }
        f32x4 acc0 = {0.f, 0.f, 0.f, 0.f}, acc1 = {0.f, 0.f, 0.f, 0.f};
#pragma unroll
        for (int kb = 0; kb < 8; ++kb) {
            acc0 = __builtin_amdgcn_mfma_f32_16x16x32_fp8_fp8(areg[0][kb], bfr[kb],
                                                              acc0, 0, 0, 0);
            acc1 = __builtin_amdgcn_mfma_f32_16x16x32_fp8_fp8(areg[1][kb], bfr[kb],
                                                              acc1, 0, 0, 0);
        }
#pragma unroll
        for (int j = 0; j < 4; ++j) {
            vmax[0][j] = fmaxf(vmax[0][j], fminf(acc0[j] + gfa[t] + nh[0][j], lwa[t]));
            vmax[1][j] = fmaxf(vmax[1][j], fminf(acc1[j] + gfa[t] + nh[1][j], lwa[t]));
        }
        __syncthreads();
    }
#undef STG

    // reduce over the 16 lr lanes (different f, same rows); direct store
#pragma unroll
    for (int m = 0; m < 2; ++m)
#pragma unroll
        for (int j = 0; j < 4; ++j) {
            float v = vmax[m][j];
            v = fmaxf(v, __shfl_xor(v, 1, 64));
            v = fmaxf(v, __shfl_xor(v, 2, 64));
            v = fmaxf(v, __shfl_xor(v, 4, 64));
            v = fmaxf(v, __shfl_xor(v, 8, 64));
            if (lr == 0) {
                int row = row0 + m * 16 + lk * 4 + j;
                nsc_part[(size_t)fs * (2 * (size_t)B * N) +
                         ((size_t)r * B + b) * N + row] = v;
            }
        }
}

// top-10 per (r,b), 256 threads, register-resident, parallel NY-fold,
// jax.lax.top_k tie-break (lower index wins on equal value)
__global__ __launch_bounds__(256) void k_topk(const float* __restrict__ nsc_part,
                                              float* __restrict__ zval,
                                              int* __restrict__ zidx, int B, int N) {
    int b = blockIdx.x, r = blockIdx.y;
    int tid = threadIdx.x, lane = tid & 63, wave = tid >> 6;
    size_t rbN = ((size_t)r * B + b) * N;
    size_t ystr = 2 * (size_t)B * N;
    // fold NY partials: 8 independent float4 loads, one latency
    const float4* p0 = (const float4*)(nsc_part + rbN) + tid;
    float4 m = *p0;
#pragma unroll
    for (int y = 1; y < NY; ++y) {
        float4 t = *(const float4*)((const float*)p0 + (size_t)y * ystr);
        m.x = fmaxf(m.x, t.x); m.y = fmaxf(m.y, t.y);
        m.z = fmaxf(m.z, t.z); m.w = fmaxf(m.w, t.w);
    }
    float v0 = expf(m.x), v1 = expf(m.y), v2 = expf(m.z), v3 = expf(m.w);
    int base = tid * 4;
    __shared__ float rv[4];
    __shared__ int ri[4];
    for (int t = 0; t < KTOP; ++t) {
        // per-thread best of 4 (strict > keeps lowest index)
        float bv = v0; int bi = base;
        if (v1 > bv) { bv = v1; bi = base + 1; }
        if (v2 > bv) { bv = v2; bi = base + 2; }
        if (v3 > bv) { bv = v3; bi = base + 3; }
        // wave reduce
#pragma unroll
        for (int off = 32; off > 0; off >>= 1) {
            float ov = __shfl_xor(bv, off, 64);
            int oi = __shfl_xor(bi, off, 64);
            if (ov > bv || (ov == bv && oi < bi)) { bv = ov; bi = oi; }
        }
        if (lane == 0) { rv[wave] = bv; ri[wave] = bi; }
        __syncthreads();
        // cross-wave fold, computed redundantly (deterministic)
        float fb = rv[0]; int fi = ri[0];
#pragma unroll
        for (int wv = 1; wv < 4; ++wv) {
            float ov = rv[wv]; int oi = ri[wv];
            if (ov > fb || (ov == fb && oi < fi)) { fb = ov; fi = oi; }
        }
        if (tid == 0) {
            zval[((size_t)r * B + b) * KTOP + t] = fb;
            zidx[((size_t)r * B + b) * KTOP + t] = fi;
        }
        // owner clears its copy (static indexing via predicated writes)
        int off = fi - base;
        v0 = (off == 0) ? -2.f : v0;
        v1 = (off == 1) ? -2.f : v1;
        v2 = (off == 2) ? -2.f : v2;
        v3 = (off == 3) ? -2.f : v3;
        __syncthreads();
    }
}

// hop2 via fp8 MFMA: 10 gathered sources (A via LDS) vs tiled fact cols (B direct).
__global__ __launch_bounds__(256) void k_hop2m(
    const unsigned char* __restrict__ entb, const unsigned char* __restrict__ fa1b,
    const unsigned char* __restrict__ fa2b, const float* __restrict__ nf1,
    const float* __restrict__ nf2, const float* __restrict__ ne,
    const float* __restrict__ lw2, const int* __restrict__ zidx,
    float* __restrict__ h2part, int B, int N, int F) {
    int L = blockIdx.x;
    int xcd = L & 7, s = L >> 3;
    int b = ((s >> 4) << 3) | xcd;
    int inner = s & 15;
    int r = inner >> 3, c = inner & 7;
    const unsigned char* factb = (r == 0) ? fa1b : fa2b;
    const float* nfp = ((r == 0) ? nf1 : nf2) + (size_t)b * F;
    const float* w = lw2 + ((size_t)r * B + b) * F;
    int tid = threadIdx.x, lane = tid & 63, wave = tid >> 6;
    int lr = lane & 15, lk = lane >> 4;
    __shared__ unsigned char aLds[32 * 16 * 8];  // [kchunk32][row16][8B] = 4KB
    __shared__ float snrm[16];
    for (int ci = tid; ci < 512; ci += 256) {
        int row = ci & 15, kc = ci >> 4;
        long vv = 0;
        if (row < KTOP) {
            int idx = zidx[((size_t)r * B + b) * KTOP + row];
            vv = *(const long*)(entb + ((size_t)b * N + idx) * E + kc * 8);
        }
        *(long*)&aLds[(size_t)ci * 8] = vv;
    }
    if (tid < 16) {
        float nv = 0.f;
        if (tid < KTOP) {
            int idx = zidx[((size_t)r * B + b) * KTOP + tid];
            nv = ne[(size_t)b * N + idx];
        }
        snrm[tid] = nv;
    }
    __syncthreads();
    long afr[8];
#pragma unroll
    for (int kb = 0; kb < 8; ++kb)
        afr[kb] = *(const long*)&aLds[((kb * 4 + lk) * 16 + lr) * 8];
    float nhs[4];
#pragma unroll
    for (int j = 0; j < 4; ++j) nhs[j] = -0.5f * snrm[lk * 4 + j];
    int fbase = c * (F >> 3) + wave * (F >> 5);  // wave's 64 cols
    float vmax[4] = {NINF, NINF, NINF, NINF};
    const unsigned char* Bb = factb + (size_t)b * F * E;
#pragma unroll
    for (int n = 0; n < 4; ++n) {
        int fcol = fbase + n * 16;
        const unsigned char* p = Bb + (size_t)(fcol >> 4) * 4096 + lk * 256 + lr * 16;
        long bfr[8];
#pragma unroll
        for (int g = 0; g < 4; ++g) {
            i64x2 vv = *(const i64x2*)(p + g * 1024);
            bfr[2 * g] = vv.x;
            bfr[2 * g + 1] = vv.y;
        }
        f32x4 acc = {0.f, 0.f, 0.f, 0.f};
#pragma unroll
        for (int kb = 0; kb < 8; ++kb)
            acc = __builtin_amdgcn_mfma_f32_16x16x32_fp8_fp8(afr[kb], bfr[kb], acc,
                                                             0, 0, 0);
        float lwf = w[fcol + lr];
        float gf = fmaf(-0.5f, nfp[fcol + lr], lwf);
#pragma unroll
        for (int j = 0; j < 4; ++j)
            vmax[j] = fmaxf(vmax[j], fminf(acc[j] + gf + nhs[j], lwf));
    }
#pragma unroll
    for (int j = 0; j < 4; ++j) {
        float v = vmax[j];
        v = fmaxf(v, __shfl_xor(v, 1, 64));
        v = fmaxf(v, __shfl_xor(v, 2, 64));
        v = fmaxf(v, __shfl_xor(v, 4, 64));
        v = fmaxf(v, __shfl_xor(v, 8, 64));
        int sidx = lk * 4 + j;
        if (lr == 0 && sidx < KTOP)
            h2part[(((size_t)r * B + b) * KTOP + sidx) * 32 + c * 4 + wave] = v;
    }
}

// combine: out[b] = max(out[b], min(exp(max_c h2part), zval))
__global__ void k_hop2c(const float* __restrict__ h2part, const float* __restrict__ zval,
                        float* __restrict__ out, int B) {
    int i = blockIdx.x * 256 + threadIdx.x;
    int n = 2 * B * KTOP;
    if (i < n) {
        int b = (i / KTOP) % B;
        float m = NINF;
#pragma unroll
        for (int c2 = 0; c2 < 32; ++c2) m = fmaxf(m, h2part[(size_t)i * 32 + c2]);
        float sc = fminf(expf(m), zval[i]);
        atomicMaxF(&out[b], sc);
    }
}

// ---------- launcher ----------
extern "C" void kernel_launch(void* const* d_in, const int* in_sizes, int n_in,
                              void* d_out, int out_size, void* d_ws, size_t ws_size,
                              hipStream_t stream) {
    const float* rel = (const float*)d_in[0];
    const float* arg1 = (const float*)d_in[1];
    const float* arg2 = (const float*)d_in[2];
    const float* frel = (const float*)d_in[3];
    const float* fa1 = (const float*)d_in[4];
    const float* fa2 = (const float*)d_in[5];
    const int* nbf = (const int*)d_in[6];
    const float* ent = (const float*)d_in[7];
    const float* W = (const float*)d_in[9];
    const float* bias = (const float*)d_in[10];
    int B = in_sizes[0] / E;
    int F = in_sizes[3] / (B * E);
    int N = in_sizes[7] / (B * E);
    float* out = (float*)d_out;

    float* ws = (float*)d_ws;
    size_t o = 0;
    float* hr = ws + o;   o += (size_t)4 * B * E;
    float* nf1 = ws + o;  o += (size_t)B * F;
    float* nf2 = ws + o;  o += (size_t)B * F;
    float* ne_ = ws + o;  o += (size_t)B * N;
    float* lw1 = ws + o;  o += (size_t)2 * B * F;
    float* lw2 = ws + o;  o += (size_t)2 * B * F;
    float* zval = ws + o; o += (size_t)2 * B * KTOP;
    int* zidx = (int*)(ws + o); o += (size_t)2 * B * KTOP;
    float* s0log = ws + o; o += (size_t)B * F;
    float* h2part = ws + o; o += (size_t)2 * B * KTOP * 32;
    float* nsc_part = ws + o; o += (size_t)NY * 2 * B * N;
    unsigned char* fa1b = (unsigned char*)(ws + o); o += (size_t)B * F * E / 4;
    unsigned char* fa2b = (unsigned char*)(ws + o); o += (size_t)B * F * E / 4;
    unsigned char* frb = (unsigned char*)(ws + o);  o += (size_t)B * F * E / 4;
    unsigned char* entb = (unsigned char*)(ws + o); o += (size_t)B * N * E / 4;
    unsigned char* entt = (unsigned char*)(ws + o); o += (size_t)B * N * E / 4;
    unsigned char* qt = (unsigned char*)(ws + o);   o += (size_t)B * 1024;

    k_hoprel<<<dim3(B, 4), dim3(E), 0, stream>>>(rel, W, bias, hr, B);
    k_prep_ent<<<dim3((B * N + 3) / 4), dim3(256), 0, stream>>>(ent, entb, entt, ne_,
                                                                B * N, N);
    k_cast<<<dim3((3 * B * F + 3) / 4), dim3(256), 0, stream>>>(frel, fa1, fa2, frb,
                                                                fa1b, fa2b, B, F);
    k_prep_q<<<dim3(B), dim3(64), 0, stream>>>(rel, arg1, arg2, hr, qt, B);
    k_pair<<<dim3(F / 64, B), dim3(256), 0, stream>>>(qt, frb, fa1b, fa2b, nbf, lw1,
                                                      lw2, s0log, nf1, nf2, B, F);
    k_s0red<<<dim3(B), dim3(256), 0, stream>>>(s0log, out, B, F);
    k_hop1m<<<dim3(2048), dim3(256), 0, stream>>>(entt, fa1b, fa2b, nf1, nf2, ne_, lw1,
                                                  nsc_part, B, N, F);
    k_topk<<<dim3(B, 2), dim3(256), 0, stream>>>(nsc_part, zval, zidx, B, N);
    k_hop2m<<<dim3(256), dim3(256), 0, stream>>>(entb, fa1b, fa2b, nf1, nf2, ne_, lw2,
                                                 zidx, h2part, B, N, F);
    k_hop2c<<<dim3((2 * B * KTOP + 255) / 256), dim3(256), 0, stream>>>(h2part, zval,
                                                                        out, B);
}

// Round 17
// 94.369 us; speedup vs baseline: 1.4986x; 1.0590x over previous
//
#include <hip/hip_runtime.h>
#include <math.h>

#define E 256
#define KTOP 10
#define NY 8
#define NINF (-__builtin_huge_valf())

typedef __attribute__((ext_vector_type(4))) float f32x4;
typedef __attribute__((ext_vector_type(2))) long i64x2;

// ---------- helpers ----------
__device__ inline float wsum(float v) {
    v += __shfl_xor(v, 1, 64);
    v += __shfl_xor(v, 2, 64);
    v += __shfl_xor(v, 4, 64);
    v += __shfl_xor(v, 8, 64);
    v += __shfl_xor(v, 16, 64);
    v += __shfl_xor(v, 32, 64);
    return v;
}

__device__ inline float wmax(float v) {
    v = fmaxf(v, __shfl_xor(v, 1, 64));
    v = fmaxf(v, __shfl_xor(v, 2, 64));
    v = fmaxf(v, __shfl_xor(v, 4, 64));
    v = fmaxf(v, __shfl_xor(v, 8, 64));
    v = fmaxf(v, __shfl_xor(v, 16, 64));
    v = fmaxf(v, __shfl_xor(v, 32, 64));
    return v;
}

__device__ inline float dot4(float4 a, float4 b) {
    return a.x * b.x + a.y * b.y + a.z * b.z + a.w * b.w;
}

__device__ inline void atomicMaxF(float* addr, float v) {
    atomicMax((unsigned int*)addr, __float_as_uint(v));  // non-negative floats
}

// f32 -> fp8 e4m3fn (OCP), RNE, saturating. Manual fallback (no API deps).
__device__ inline unsigned char f2fp8(float x) {
    unsigned u = __float_as_uint(x);
    unsigned s = (u >> 24) & 0x80u;
    int e = (int)((u >> 23) & 0xFF) - 127;
    unsigned m = u & 0x7FFFFFu;
    if (e < -9) return (unsigned char)s;                 // -> 0
    if (e > 8) return (unsigned char)(s | 0x7E);         // saturate to 448
    if (e >= -6) {                                       // normal
        unsigned mant = m >> 20;
        unsigned rest = m & 0xFFFFFu;
        if (rest > 0x80000u || (rest == 0x80000u && (mant & 1))) mant++;
        unsigned v = (((unsigned)(e + 7)) << 3) + mant;  // carry into exp is fine
        if (v > 0x7Eu) v = 0x7Eu;
        return (unsigned char)(s | v);
    }
    int rs = 20 + (-6 - e);                              // subnormal, shift 1..3
    unsigned full = 0x800000u | m;
    unsigned mant = full >> rs;
    unsigned rem = full & ((1u << rs) - 1u);
    unsigned half = 1u << (rs - 1);
    if (rem > half || (rem == half && (mant & 1))) mant++;
    if (mant >= 8u) return (unsigned char)(s | 0x08u);
    return (unsigned char)(s | mant);
}

#if defined(__has_builtin)
#if __has_builtin(__builtin_amdgcn_cvt_pk_fp8_f32)
#define HAVE_HW_FP8 1
#endif
#endif

// 4x f32 -> packed fp8 dword (bytes [a,b,c,d] little-endian)
__device__ inline unsigned pack_fp8x4(float a, float b, float c, float d) {
#ifdef HAVE_HW_FP8
    int lo = __builtin_amdgcn_cvt_pk_fp8_f32(a, b, 0, false);
    return (unsigned)__builtin_amdgcn_cvt_pk_fp8_f32(c, d, lo, true);
#else
    return (unsigned)f2fp8(a) | ((unsigned)f2fp8(b) << 8) |
           ((unsigned)f2fp8(c) << 16) | ((unsigned)f2fp8(d) << 24);
#endif
}

// fp8 tile layout (4096B per 16-col tile), [g][lk][col] order:
// byte(e, col) = (e>>6)*1024 + ((e&31)>>3)*256 + col*16 + ((e>>5)&1)*8 + (e&7)
// => MFMA fragment read for lane (col=lr, lk) at g*1024 + lane*16 (contiguous).
__device__ inline int tile_off(int e0, int col) {
    return ((e0 >> 6) << 10) + (((e0 & 31) >> 3) << 8) + (col << 4) +
           (((e0 >> 5) & 1) << 3) + (e0 & 7);
}

// ---------- kernels ----------
// hop_rel rows only (norms come from MFMA Q.Q diagonal)
__global__ void k_hoprel(const float* __restrict__ rel, const float* __restrict__ W,
                         const float* __restrict__ bias, float* __restrict__ hr,
                         int B) {
    int b = blockIdx.x, rh = blockIdx.y;
    int j = threadIdx.x;  // 0..255
    __shared__ float relS[E];
    relS[j] = rel[b * E + j];
    __syncthreads();
    const float* Wp = W + (size_t)rh * E * E;
    float acc = bias[rh * E + j];
#pragma unroll 8
    for (int e = 0; e < E; ++e) acc = fmaf(relS[e], Wp[e * E + j], acc);
    hr[((size_t)rh * B + b) * E + j] = acc;
}

// ent: norms + fp8 row-major (hop2 gather) + fp8 tiled (hop1 A-side)
__global__ void k_prep_ent(const float* __restrict__ ent, unsigned char* __restrict__ entb,
                           unsigned char* __restrict__ entt, float* __restrict__ ne_,
                           int BN, int N) {
    int row = blockIdx.x * 4 + (threadIdx.x >> 6);
    if (row >= BN) return;
    int lane = threadIdx.x & 63;
    float4 v = ((const float4*)(ent + (size_t)row * E))[lane];
    float s = wsum(dot4(v, v));
    if (lane == 0) ne_[row] = s;
    unsigned o = pack_fp8x4(v.x, v.y, v.z, v.w);
    ((unsigned*)(entb + (size_t)row * E))[lane] = o;
    int b = row / N, n = row % N;
    size_t tbase = ((size_t)b * (N >> 4) + (n >> 4)) * 4096;
    *(unsigned*)(entt + tbase + tile_off(lane * 4, n & 15)) = o;
}

// per-b fp8 query tile: rows {rel, arg1, arg2, hr00, hr01, hr10, hr11}, rest 0
__global__ __launch_bounds__(64) void k_prep_q(
    const float* __restrict__ rel, const float* __restrict__ arg1,
    const float* __restrict__ arg2, const float* __restrict__ hr,
    unsigned char* __restrict__ qt, int B) {
    int b = blockIdx.x;
    int lane = threadIdx.x;
    unsigned char* t = qt + (size_t)b * 4096;
#define ROW(q, ptr)                                                       \
    {                                                                     \
        float4 v = ((const float4*)(ptr))[lane];                          \
        *(unsigned*)(t + tile_off(lane * 4, q)) =                         \
            pack_fp8x4(v.x, v.y, v.z, v.w);                               \
    }
    ROW(0, rel + (size_t)b * E)
    ROW(1, arg1 + (size_t)b * E)
    ROW(2, arg2 + (size_t)b * E)
    ROW(3, hr + ((size_t)0 * B + b) * E)
    ROW(4, hr + ((size_t)1 * B + b) * E)
    ROW(5, hr + ((size_t)2 * B + b) * E)
    ROW(6, hr + ((size_t)3 * B + b) * E)
#undef ROW
#pragma unroll
    for (int q = 7; q < 16; ++q)
        *(unsigned*)(t + tile_off(lane * 4, q)) = 0u;
}

// fused cast+pair: block = one 16-fact tile. Coalesced f32 reads -> fp8 LDS
// tiles; fa1b/fa2b written as contiguous block copies; frel tile consumed
// in-LDS (never hits global). Wave 0 computes all dots/norms via fp8 MFMA.
__global__ __launch_bounds__(256) void k_castpair(
    const float* __restrict__ frel, const float* __restrict__ fa1,
    const float* __restrict__ fa2, const unsigned char* __restrict__ qt,
    const int* __restrict__ nbf, float* __restrict__ lw1, float* __restrict__ lw2,
    float* __restrict__ s0log, float* __restrict__ nf1, float* __restrict__ nf2,
    unsigned char* __restrict__ fa1b, unsigned char* __restrict__ fa2b,
    int B, int F) {
    int ti = blockIdx.x, b = blockIdx.y;
    int f0 = ti * 16;
    int tid = threadIdx.x;
    __shared__ unsigned char sFR[4096], sF1[4096], sF2[4096];
    __shared__ float vals[16][12];
    __shared__ float qn[8];
    // stage: row = tid>>4 (tile col), 16 lanes x float4 = 256B segments
    int row = tid >> 4;
    int cb = (tid & 15) * 4;
    size_t rbase = ((size_t)b * F + f0 + row) * E;
#pragma unroll
    for (int p = 0; p < 4; ++p) {
        int e0 = p * 64 + cb;
        float4 vr = *(const float4*)(frel + rbase + e0);
        float4 v1 = *(const float4*)(fa1 + rbase + e0);
        float4 v2 = *(const float4*)(fa2 + rbase + e0);
        int off = tile_off(e0, row);
        *(unsigned*)&sFR[off] = pack_fp8x4(vr.x, vr.y, vr.z, vr.w);
        *(unsigned*)&sF1[off] = pack_fp8x4(v1.x, v1.y, v1.z, v1.w);
        *(unsigned*)&sF2[off] = pack_fp8x4(v2.x, v2.y, v2.z, v2.w);
    }
    __syncthreads();
    // coalesced tile stores (LDS and global layouts identical)
    size_t tb = ((size_t)b * (F >> 4) + ti) * 4096;
    *(i64x2*)(fa1b + tb + tid * 16) = *(const i64x2*)&sF1[tid * 16];
    *(i64x2*)(fa2b + tb + tid * 16) = *(const i64x2*)&sF2[tid * 16];
    if (tid >= 64) return;  // wave 0 does the MFMA + epilogue
    int lane = tid, lr = lane & 15, lk = lane >> 4;
    const unsigned char* qp = qt + (size_t)b * 4096 + lane * 16;
    long Q[8], FR[8], F1[8], F2[8];
#pragma unroll
    for (int g = 0; g < 4; ++g) {
        i64x2 a = *(const i64x2*)(qp + g * 1024);
        Q[2 * g] = a.x; Q[2 * g + 1] = a.y;
        i64x2 c = *(const i64x2*)&sFR[g * 1024 + lane * 16];
        FR[2 * g] = c.x; FR[2 * g + 1] = c.y;
        i64x2 d = *(const i64x2*)&sF1[g * 1024 + lane * 16];
        F1[2 * g] = d.x; F1[2 * g + 1] = d.y;
        i64x2 e2 = *(const i64x2*)&sF2[g * 1024 + lane * 16];
        F2[2 * g] = e2.x; F2[2 * g + 1] = e2.y;
    }
    f32x4 Dqq = {0.f, 0.f, 0.f, 0.f}, D1 = Dqq, D2 = Dqq, D3 = Dqq, D4 = Dqq,
          D5 = Dqq, D6 = Dqq;
#pragma unroll
    for (int kb = 0; kb < 8; ++kb) {
        Dqq = __builtin_amdgcn_mfma_f32_16x16x32_fp8_fp8(Q[kb], Q[kb], Dqq, 0, 0, 0);
        D1 = __builtin_amdgcn_mfma_f32_16x16x32_fp8_fp8(Q[kb], FR[kb], D1, 0, 0, 0);
        D2 = __builtin_amdgcn_mfma_f32_16x16x32_fp8_fp8(Q[kb], F1[kb], D2, 0, 0, 0);
        D3 = __builtin_amdgcn_mfma_f32_16x16x32_fp8_fp8(Q[kb], F2[kb], D3, 0, 0, 0);
        D4 = __builtin_amdgcn_mfma_f32_16x16x32_fp8_fp8(FR[kb], FR[kb], D4, 0, 0, 0);
        D5 = __builtin_amdgcn_mfma_f32_16x16x32_fp8_fp8(F1[kb], F1[kb], D5, 0, 0, 0);
        D6 = __builtin_amdgcn_mfma_f32_16x16x32_fp8_fp8(F2[kb], F2[kb], D6, 0, 0, 0);
    }
    // scatter needed values (wave-local LDS, same-wave ordering)
#pragma unroll
    for (int j = 0; j < 4; ++j) {
        int q = lk * 4 + j;
        if (q == 0) vals[lr][0] = D1[j];   // rel . fr
        if (q == 3) vals[lr][1] = D1[j];   // h00 . fr
        if (q == 4) vals[lr][2] = D1[j];   // h01 . fr
        if (q == 5) vals[lr][3] = D1[j];   // h10 . fr
        if (q == 6) vals[lr][4] = D1[j];   // h11 . fr
        if (q == 1) { vals[lr][5] = D2[j]; vals[lr][7] = D3[j]; }
        if (q == 2) { vals[lr][6] = D2[j]; vals[lr][8] = D3[j]; }
        if (q == lr) {
            vals[lr][9] = D4[j];   // |fr|^2
            vals[lr][10] = D5[j];  // |f1|^2
            vals[lr][11] = D6[j];  // |f2|^2
            if (q < 7) qn[q] = Dqq[j];
        }
    }
    if (lane < 16) {
        int f = f0 + lane;
        size_t bf = (size_t)b * F + f;
        const float* vv = vals[lane];
        float nfr = vv[9], n1 = vv[10], n2 = vv[11];
        bool msk = (f < nbf[b]);
        float rrel  = fmaxf(qn[0] + nfr - 2.f * vv[0], 0.f);
        float rh00  = fmaxf(qn[3] + nfr - 2.f * vv[1], 0.f);
        float rh01  = fmaxf(qn[4] + nfr - 2.f * vv[2], 0.f);
        float rh10  = fmaxf(qn[5] + nfr - 2.f * vv[3], 0.f);
        float rh11  = fmaxf(qn[6] + nfr - 2.f * vv[4], 0.f);
        float ra1f1 = fmaxf(qn[1] + n1 - 2.f * vv[5], 0.f);
        float ra2f1 = fmaxf(qn[2] + n1 - 2.f * vv[6], 0.f);
        float ra1f2 = fmaxf(qn[1] + n2 - 2.f * vv[7], 0.f);
        float ra2f2 = fmaxf(qn[2] + n2 - 2.f * vv[8], 0.f);
        nf1[bf] = n1;
        nf2[bf] = n2;
        lw1[bf]                 = msk ? -0.5f * (rh00 + ra1f1) : NINF;
        lw1[(size_t)B * F + bf] = msk ? -0.5f * (rh10 + ra1f2) : NINF;
        lw2[bf]                 = msk ? -0.5f * (rh01 + ra2f2) : NINF;
        lw2[(size_t)B * F + bf] = msk ? -0.5f * (rh11 + ra2f1) : NINF;
        s0log[bf] = msk ? -0.5f * (rrel + ra1f1 + ra2f2) : NINF;
    }
}

// out[b] = exp(max_f s0log[b][f])
__global__ void k_s0red(const float* __restrict__ s0log, float* __restrict__ out,
                        int B, int F) {
    int b = blockIdx.x;
    int tid = threadIdx.x, lane = tid & 63, wave = tid >> 6;
    float m = NINF;
    for (int f = tid; f < F; f += 256) m = fmaxf(m, s0log[(size_t)b * F + f]);
    m = wmax(m);
    __shared__ float red[4];
    if (lane == 0) red[wave] = m;
    __syncthreads();
    if (tid == 0) out[b] = expf(fmaxf(fmaxf(red[0], red[1]), fmaxf(red[2], red[3])));
}

// hop1: fp8 MFMA. A (32 rows/wave) in regs from tiled ent; B staged to LDS once
// per block, double-buffered, shared by 4 waves; conflict-free contiguous reads.
// Grid 2048: b(16) x r(2) x nb(8: 128-row) x fs(8: 256-col), XCD-swizzled.
__global__ __launch_bounds__(256, 4) void k_hop1m(
    const unsigned char* __restrict__ entt, const unsigned char* __restrict__ fa1b,
    const unsigned char* __restrict__ fa2b, const float* __restrict__ nf1,
    const float* __restrict__ nf2, const float* __restrict__ ne,
    const float* __restrict__ lw1, float* __restrict__ nsc_part, int B, int N, int F) {
    int L = blockIdx.x;
    int xcd = L & 7, s = L >> 3;
    int b = ((s >> 7) << 3) | xcd;  // batch-pair {xcd, xcd+8} per XCD
    int inner = s & 127;
    int r = inner >> 6, nb = (inner >> 3) & 7, fs = inner & 7;
    int BR = nb * 128;
    int F0 = fs * 256;
    const unsigned char* factb = (r == 0) ? fa2b : fa1b;
    const float* nfp = ((r == 0) ? nf2 : nf1) + (size_t)b * F;
    const float* w = lw1 + ((size_t)r * B + b) * F;
    const float* nep = ne + (size_t)b * N;

    __shared__ unsigned char bT[2][4096];

    int tid = threadIdx.x, lane = tid & 63, wave = tid >> 6;
    int lr = lane & 15, lk = lane >> 4;
    int row0 = BR + wave * 32;

    // A fragments: 2 m-frags x 8 kb; [g][lk][col] layout -> contiguous 16B loads
    const unsigned char* At = entt + (size_t)b * N * E;
    long areg[2][8];
#pragma unroll
    for (int m = 0; m < 2; ++m) {
        const unsigned char* p = At + (size_t)((row0 >> 4) + m) * 4096 + lk * 256 +
                                 lr * 16;
#pragma unroll
        for (int g = 0; g < 4; ++g) {
            i64x2 vv = *(const i64x2*)(p + g * 1024);
            areg[m][2 * g] = vv.x;
            areg[m][2 * g + 1] = vv.y;
        }
    }
    float nh[2][4];
#pragma unroll
    for (int m = 0; m < 2; ++m)
#pragma unroll
        for (int j = 0; j < 4; ++j)
            nh[m][j] = -0.5f * nep[row0 + m * 16 + lk * 4 + j];
    // preload per-tile lw / gf (statically indexed; t-loop fully unrolled)
    float lwa[16], gfa[16];
#pragma unroll
    for (int t = 0; t < 16; ++t) {
        int fcol = F0 + t * 16 + lr;
        lwa[t] = w[fcol];
        gfa[t] = fmaf(-0.5f, nfp[fcol], lwa[t]);
    }
    float vmax[2][4];
#pragma unroll
    for (int m = 0; m < 2; ++m)
#pragma unroll
        for (int j = 0; j < 4; ++j) vmax[m][j] = NINF;

    const unsigned char* Bt = factb + (size_t)b * F * E + (size_t)(F0 >> 4) * 4096;
#define STG(buf, t)                                                            \
    __builtin_amdgcn_global_load_lds(                                          \
        (const __attribute__((address_space(1))) void*)(Bt + (size_t)(t) * 4096 + \
                                                        wave * 1024 + lane * 16), \
        (__attribute__((address_space(3))) void*)&bT[buf][wave * 1024], 16, 0, 0)

    STG(0, 0);
    __syncthreads();
#pragma unroll
    for (int t = 0; t < 16; ++t) {
        int cur = t & 1;
        if (t < 15) STG(cur ^ 1, t + 1);
        long bfr[8];
#pragma unroll
        for (int g = 0; g < 4; ++g) {
            i64x2 vv = *(const i64x2*)&bT[cur][g * 1024 + lane * 16];
            bfr[2 * g] = vv.x;
            bfr[2 * g + 1] = vv.y;
        }
        f32x4 acc0 = {0.f, 0.f, 0.f, 0.f}, acc1 = {0.f, 0.f, 0.f, 0.f};
#pragma unroll
        for (int kb = 0; kb < 8; ++kb) {
            acc0 = __builtin_amdgcn_mfma_f32_16x16x32_fp8_fp8(areg[0][kb], bfr[kb],
                                                              acc0, 0, 0, 0);
            acc1 = __builtin_amdgcn_mfma_f32_16x16x32_fp8_fp8(areg[1][kb], bfr[kb],
                                                              acc1, 0, 0, 0);
        }
#pragma unroll
        for (int j = 0; j < 4; ++j) {
            vmax[0][j] = fmaxf(vmax[0][j], fminf(acc0[j] + gfa[t] + nh[0][j], lwa[t]));
            vmax[1][j] = fmaxf(vmax[1][j], fminf(acc1[j] + gfa[t] + nh[1][j], lwa[t]));
        }
        __syncthreads();
    }
#undef STG

    // reduce over the 16 lr lanes (different f, same rows); direct store
#pragma unroll
    for (int m = 0; m < 2; ++m)
#pragma unroll
        for (int j = 0; j < 4; ++j) {
            float v = vmax[m][j];
            v = fmaxf(v, __shfl_xor(v, 1, 64));
            v = fmaxf(v, __shfl_xor(v, 2, 64));
            v = fmaxf(v, __shfl_xor(v, 4, 64));
            v = fmaxf(v, __shfl_xor(v, 8, 64));
            if (lr == 0) {
                int row = row0 + m * 16 + lk * 4 + j;
                nsc_part[(size_t)fs * (2 * (size_t)B * N) +
                         ((size_t)r * B + b) * N + row] = v;
            }
        }
}

// top-10 per (r,b), 256 threads, register-resident, parallel NY-fold,
// jax.lax.top_k tie-break (lower index wins on equal value)
__global__ __launch_bounds__(256) void k_topk(const float* __restrict__ nsc_part,
                                              float* __restrict__ zval,
                                              int* __restrict__ zidx, int B, int N) {
    int b = blockIdx.x, r = blockIdx.y;
    int tid = threadIdx.x, lane = tid & 63, wave = tid >> 6;
    size_t rbN = ((size_t)r * B + b) * N;
    size_t ystr = 2 * (size_t)B * N;
    // fold NY partials: 8 independent float4 loads, one latency
    const float4* p0 = (const float4*)(nsc_part + rbN) + tid;
    float4 m = *p0;
#pragma unroll
    for (int y = 1; y < NY; ++y) {
        float4 t = *(const float4*)((const float*)p0 + (size_t)y * ystr);
        m.x = fmaxf(m.x, t.x); m.y = fmaxf(m.y, t.y);
        m.z = fmaxf(m.z, t.z); m.w = fmaxf(m.w, t.w);
    }
    float v0 = expf(m.x), v1 = expf(m.y), v2 = expf(m.z), v3 = expf(m.w);
    int base = tid * 4;
    __shared__ float rv[4];
    __shared__ int ri[4];
    for (int t = 0; t < KTOP; ++t) {
        // per-thread best of 4 (strict > keeps lowest index)
        float bv = v0; int bi = base;
        if (v1 > bv) { bv = v1; bi = base + 1; }
        if (v2 > bv) { bv = v2; bi = base + 2; }
        if (v3 > bv) { bv = v3; bi = base + 3; }
        // wave reduce
#pragma unroll
        for (int off = 32; off > 0; off >>= 1) {
            float ov = __shfl_xor(bv, off, 64);
            int oi = __shfl_xor(bi, off, 64);
            if (ov > bv || (ov == bv && oi < bi)) { bv = ov; bi = oi; }
        }
        if (lane == 0) { rv[wave] = bv; ri[wave] = bi; }
        __syncthreads();
        // cross-wave fold, computed redundantly (deterministic)
        float fb = rv[0]; int fi = ri[0];
#pragma unroll
        for (int wv = 1; wv < 4; ++wv) {
            float ov = rv[wv]; int oi = ri[wv];
            if (ov > fb || (ov == fb && oi < fi)) { fb = ov; fi = oi; }
        }
        if (tid == 0) {
            zval[((size_t)r * B + b) * KTOP + t] = fb;
            zidx[((size_t)r * B + b) * KTOP + t] = fi;
        }
        // owner clears its copy (static indexing via predicated writes)
        int off = fi - base;
        v0 = (off == 0) ? -2.f : v0;
        v1 = (off == 1) ? -2.f : v1;
        v2 = (off == 2) ? -2.f : v2;
        v3 = (off == 3) ? -2.f : v3;
        __syncthreads();
    }
}

// hop2 via fp8 MFMA: 10 gathered sources (A via LDS) vs tiled fact cols (B direct).
__global__ __launch_bounds__(256) void k_hop2m(
    const unsigned char* __restrict__ entb, const unsigned char* __restrict__ fa1b,
    const unsigned char* __restrict__ fa2b, const float* __restrict__ nf1,
    const float* __restrict__ nf2, const float* __restrict__ ne,
    const float* __restrict__ lw2, const int* __restrict__ zidx,
    float* __restrict__ h2part, int B, int N, int F) {
    int L = blockIdx.x;
    int xcd = L & 7, s = L >> 3;
    int b = ((s >> 4) << 3) | xcd;
    int inner = s & 15;
    int r = inner >> 3, c = inner & 7;
    const unsigned char* factb = (r == 0) ? fa1b : fa2b;
    const float* nfp = ((r == 0) ? nf1 : nf2) + (size_t)b * F;
    const float* w = lw2 + ((size_t)r * B + b) * F;
    int tid = threadIdx.x, lane = tid & 63, wave = tid >> 6;
    int lr = lane & 15, lk = lane >> 4;
    __shared__ unsigned char aLds[32 * 16 * 8];  // [kchunk32][row16][8B] = 4KB
    __shared__ float snrm[16];
    for (int ci = tid; ci < 512; ci += 256) {
        int row = ci & 15, kc = ci >> 4;
        long vv = 0;
        if (row < KTOP) {
            int idx = zidx[((size_t)r * B + b) * KTOP + row];
            vv = *(const long*)(entb + ((size_t)b * N + idx) * E + kc * 8);
        }
        *(long*)&aLds[(size_t)ci * 8] = vv;
    }
    if (tid < 16) {
        float nv = 0.f;
        if (tid < KTOP) {
            int idx = zidx[((size_t)r * B + b) * KTOP + tid];
            nv = ne[(size_t)b * N + idx];
        }
        snrm[tid] = nv;
    }
    __syncthreads();
    long afr[8];
#pragma unroll
    for (int kb = 0; kb < 8; ++kb)
        afr[kb] = *(const long*)&aLds[((kb * 4 + lk) * 16 + lr) * 8];
    float nhs[4];
#pragma unroll
    for (int j = 0; j < 4; ++j) nhs[j] = -0.5f * snrm[lk * 4 + j];
    int fbase = c * (F >> 3) + wave * (F >> 5);  // wave's 64 cols
    float vmax[4] = {NINF, NINF, NINF, NINF};
    const unsigned char* Bb = factb + (size_t)b * F * E;
#pragma unroll
    for (int n = 0; n < 4; ++n) {
        int fcol = fbase + n * 16;
        const unsigned char* p = Bb + (size_t)(fcol >> 4) * 4096 + lk * 256 + lr * 16;
        long bfr[8];
#pragma unroll
        for (int g = 0; g < 4; ++g) {
            i64x2 vv = *(const i64x2*)(p + g * 1024);
            bfr[2 * g] = vv.x;
            bfr[2 * g + 1] = vv.y;
        }
        f32x4 acc = {0.f, 0.f, 0.f, 0.f};
#pragma unroll
        for (int kb = 0; kb < 8; ++kb)
            acc = __builtin_amdgcn_mfma_f32_16x16x32_fp8_fp8(afr[kb], bfr[kb], acc,
                                                             0, 0, 0);
        float lwf = w[fcol + lr];
        float gf = fmaf(-0.5f, nfp[fcol + lr], lwf);
#pragma unroll
        for (int j = 0; j < 4; ++j)
            vmax[j] = fmaxf(vmax[j], fminf(acc[j] + gf + nhs[j], lwf));
    }
#pragma unroll
    for (int j = 0; j < 4; ++j) {
        float v = vmax[j];
        v = fmaxf(v, __shfl_xor(v, 1, 64));
        v = fmaxf(v, __shfl_xor(v, 2, 64));
        v = fmaxf(v, __shfl_xor(v, 4, 64));
        v = fmaxf(v, __shfl_xor(v, 8, 64));
        int sidx = lk * 4 + j;
        if (lr == 0 && sidx < KTOP)
            h2part[(((size_t)r * B + b) * KTOP + sidx) * 32 + c * 4 + wave] = v;
    }
}

// combine: out[b] = max(out[b], min(exp(max_c h2part), zval))
__global__ void k_hop2c(const float* __restrict__ h2part, const float* __restrict__ zval,
                        float* __restrict__ out, int B) {
    int i = blockIdx.x * 256 + threadIdx.x;
    int n = 2 * B * KTOP;
    if (i < n) {
        int b = (i / KTOP) % B;
        float m = NINF;
#pragma unroll
        for (int c2 = 0; c2 < 32; ++c2) m = fmaxf(m, h2part[(size_t)i * 32 + c2]);
        float sc = fminf(expf(m), zval[i]);
        atomicMaxF(&out[b], sc);
    }
}

// ---------- launcher ----------
extern "C" void kernel_launch(void* const* d_in, const int* in_sizes, int n_in,
                              void* d_out, int out_size, void* d_ws, size_t ws_size,
                              hipStream_t stream) {
    const float* rel = (const float*)d_in[0];
    const float* arg1 = (const float*)d_in[1];
    const float* arg2 = (const float*)d_in[2];
    const float* frel = (const float*)d_in[3];
    const float* fa1 = (const float*)d_in[4];
    const float* fa2 = (const float*)d_in[5];
    const int* nbf = (const int*)d_in[6];
    const float* ent = (const float*)d_in[7];
    const float* W = (const float*)d_in[9];
    const float* bias = (const float*)d_in[10];
    int B = in_sizes[0] / E;
    int F = in_sizes[3] / (B * E);
    int N = in_sizes[7] / (B * E);
    float* out = (float*)d_out;

    float* ws = (float*)d_ws;
    size_t o = 0;
    float* hr = ws + o;   o += (size_t)4 * B * E;
    float* nf1 = ws + o;  o += (size_t)B * F;
    float* nf2 = ws + o;  o += (size_t)B * F;
    float* ne_ = ws + o;  o += (size_t)B * N;
    float* lw1 = ws + o;  o += (size_t)2 * B * F;
    float* lw2 = ws + o;  o += (size_t)2 * B * F;
    float* zval = ws + o; o += (size_t)2 * B * KTOP;
    int* zidx = (int*)(ws + o); o += (size_t)2 * B * KTOP;
    float* s0log = ws + o; o += (size_t)B * F;
    float* h2part = ws + o; o += (size_t)2 * B * KTOP * 32;
    float* nsc_part = ws + o; o += (size_t)NY * 2 * B * N;
    unsigned char* fa1b = (unsigned char*)(ws + o); o += (size_t)B * F * E / 4;
    unsigned char* fa2b = (unsigned char*)(ws + o); o += (size_t)B * F * E / 4;
    unsigned char* entb = (unsigned char*)(ws + o); o += (size_t)B * N * E / 4;
    unsigned char* entt = (unsigned char*)(ws + o); o += (size_t)B * N * E / 4;
    unsigned char* qt = (unsigned char*)(ws + o);   o += (size_t)B * 1024;

    k_hoprel<<<dim3(B, 4), dim3(E), 0, stream>>>(rel, W, bias, hr, B);
    k_prep_ent<<<dim3((B * N + 3) / 4), dim3(256), 0, stream>>>(ent, entb, entt, ne_,
                                                                B * N, N);
    k_prep_q<<<dim3(B), dim3(64), 0, stream>>>(rel, arg1, arg2, hr, qt, B);
    k_castpair<<<dim3(F / 16, B), dim3(256), 0, stream>>>(
        frel, fa1, fa2, qt, nbf, lw1, lw2, s0log, nf1, nf2, fa1b, fa2b, B, F);
    k_s0red<<<dim3(B), dim3(256), 0, stream>>>(s0log, out, B, F);
    k_hop1m<<<dim3(2048), dim3(256), 0, stream>>>(entt, fa1b, fa2b, nf1, nf2, ne_, lw1,
                                                  nsc_part, B, N, F);
    k_topk<<<dim3(B, 2), dim3(256), 0, stream>>>(nsc_part, zval, zidx, B, N);
    k_hop2m<<<dim3(256), dim3(256), 0, stream>>>(entb, fa1b, fa2b, nf1, nf2, ne_, lw2,
                                                 zidx, h2part, B, N, F);
    k_hop2c<<<dim3((2 * B * KTOP + 255) / 256), dim3(256), 0, stream>>>(h2part, zval,
                                                                        out, B);
}

// Round 18
// 93.889 us; speedup vs baseline: 1.5062x; 1.0051x over previous
//
#include <hip/hip_runtime.h>
#include <math.h>

#define E 256
#define KTOP 10
#define NY 8
#define NINF (-__builtin_huge_valf())

typedef __attribute__((ext_vector_type(4))) float f32x4;
typedef __attribute__((ext_vector_type(2))) long i64x2;

// ---------- helpers ----------
__device__ inline float wsum(float v) {
    v += __shfl_xor(v, 1, 64);
    v += __shfl_xor(v, 2, 64);
    v += __shfl_xor(v, 4, 64);
    v += __shfl_xor(v, 8, 64);
    v += __shfl_xor(v, 16, 64);
    v += __shfl_xor(v, 32, 64);
    return v;
}

__device__ inline float wmax(float v) {
    v = fmaxf(v, __shfl_xor(v, 1, 64));
    v = fmaxf(v, __shfl_xor(v, 2, 64));
    v = fmaxf(v, __shfl_xor(v, 4, 64));
    v = fmaxf(v, __shfl_xor(v, 8, 64));
    v = fmaxf(v, __shfl_xor(v, 16, 64));
    v = fmaxf(v, __shfl_xor(v, 32, 64));
    return v;
}

__device__ inline float dot4(float4 a, float4 b) {
    return a.x * b.x + a.y * b.y + a.z * b.z + a.w * b.w;
}

__device__ inline void atomicMaxF(float* addr, float v) {
    atomicMax((unsigned int*)addr, __float_as_uint(v));  // non-negative floats
}

// f32 -> fp8 e4m3fn (OCP), RNE, saturating. Manual fallback (no API deps).
__device__ inline unsigned char f2fp8(float x) {
    unsigned u = __float_as_uint(x);
    unsigned s = (u >> 24) & 0x80u;
    int e = (int)((u >> 23) & 0xFF) - 127;
    unsigned m = u & 0x7FFFFFu;
    if (e < -9) return (unsigned char)s;                 // -> 0
    if (e > 8) return (unsigned char)(s | 0x7E);         // saturate to 448
    if (e >= -6) {                                       // normal
        unsigned mant = m >> 20;
        unsigned rest = m & 0xFFFFFu;
        if (rest > 0x80000u || (rest == 0x80000u && (mant & 1))) mant++;
        unsigned v = (((unsigned)(e + 7)) << 3) + mant;  // carry into exp is fine
        if (v > 0x7Eu) v = 0x7Eu;
        return (unsigned char)(s | v);
    }
    int rs = 20 + (-6 - e);                              // subnormal, shift 1..3
    unsigned full = 0x800000u | m;
    unsigned mant = full >> rs;
    unsigned rem = full & ((1u << rs) - 1u);
    unsigned half = 1u << (rs - 1);
    if (rem > half || (rem == half && (mant & 1))) mant++;
    if (mant >= 8u) return (unsigned char)(s | 0x08u);
    return (unsigned char)(s | mant);
}

#if defined(__has_builtin)
#if __has_builtin(__builtin_amdgcn_cvt_pk_fp8_f32)
#define HAVE_HW_FP8 1
#endif
#endif

// 4x f32 -> packed fp8 dword (bytes [a,b,c,d] little-endian)
__device__ inline unsigned pack_fp8x4(float a, float b, float c, float d) {
#ifdef HAVE_HW_FP8
    int lo = __builtin_amdgcn_cvt_pk_fp8_f32(a, b, 0, false);
    return (unsigned)__builtin_amdgcn_cvt_pk_fp8_f32(c, d, lo, true);
#else
    return (unsigned)f2fp8(a) | ((unsigned)f2fp8(b) << 8) |
           ((unsigned)f2fp8(c) << 16) | ((unsigned)f2fp8(d) << 24);
#endif
}

// fp8 tile layout (4096B per 16-col tile), [g][lk][col] order:
// byte(e, col) = (e>>6)*1024 + ((e&31)>>3)*256 + col*16 + ((e>>5)&1)*8 + (e&7)
// => MFMA fragment read for lane (col=lr, lk) at g*1024 + lane*16 (contiguous).
__device__ inline int tile_off(int e0, int col) {
    return ((e0 >> 6) << 10) + (((e0 & 31) >> 3) << 8) + (col << 4) +
           (((e0 >> 5) & 1) << 3) + (e0 & 7);
}

// ---------- kernels ----------
// hop_rel rows only (norms come from MFMA Q.Q diagonal)
__global__ void k_hoprel(const float* __restrict__ rel, const float* __restrict__ W,
                         const float* __restrict__ bias, float* __restrict__ hr,
                         int B) {
    int b = blockIdx.x, rh = blockIdx.y;
    int j = threadIdx.x;  // 0..255
    __shared__ float relS[E];
    relS[j] = rel[b * E + j];
    __syncthreads();
    const float* Wp = W + (size_t)rh * E * E;
    float acc = bias[rh * E + j];
#pragma unroll 8
    for (int e = 0; e < E; ++e) acc = fmaf(relS[e], Wp[e * E + j], acc);
    hr[((size_t)rh * B + b) * E + j] = acc;
}

// ent: norms + fp8 row-major (hop2 gather) + fp8 tiled (hop1 A-side)
__global__ void k_prep_ent(const float* __restrict__ ent, unsigned char* __restrict__ entb,
                           unsigned char* __restrict__ entt, float* __restrict__ ne_,
                           int BN, int N) {
    int row = blockIdx.x * 4 + (threadIdx.x >> 6);
    if (row >= BN) return;
    int lane = threadIdx.x & 63;
    float4 v = ((const float4*)(ent + (size_t)row * E))[lane];
    float s = wsum(dot4(v, v));
    if (lane == 0) ne_[row] = s;
    unsigned o = pack_fp8x4(v.x, v.y, v.z, v.w);
    ((unsigned*)(entb + (size_t)row * E))[lane] = o;
    int b = row / N, n = row % N;
    size_t tbase = ((size_t)b * (N >> 4) + (n >> 4)) * 4096;
    *(unsigned*)(entt + tbase + tile_off(lane * 4, n & 15)) = o;
}

// per-b fp8 query tile: rows {rel, arg1, arg2, hr00, hr01, hr10, hr11}, rest 0
__global__ __launch_bounds__(64) void k_prep_q(
    const float* __restrict__ rel, const float* __restrict__ arg1,
    const float* __restrict__ arg2, const float* __restrict__ hr,
    unsigned char* __restrict__ qt, int B) {
    int b = blockIdx.x;
    int lane = threadIdx.x;
    unsigned char* t = qt + (size_t)b * 4096;
#define ROW(q, ptr)                                                       \
    {                                                                     \
        float4 v = ((const float4*)(ptr))[lane];                          \
        *(unsigned*)(t + tile_off(lane * 4, q)) =                         \
            pack_fp8x4(v.x, v.y, v.z, v.w);                               \
    }
    ROW(0, rel + (size_t)b * E)
    ROW(1, arg1 + (size_t)b * E)
    ROW(2, arg2 + (size_t)b * E)
    ROW(3, hr + ((size_t)0 * B + b) * E)
    ROW(4, hr + ((size_t)1 * B + b) * E)
    ROW(5, hr + ((size_t)2 * B + b) * E)
    ROW(6, hr + ((size_t)3 * B + b) * E)
#undef ROW
#pragma unroll
    for (int q = 7; q < 16; ++q)
        *(unsigned*)(t + tile_off(lane * 4, q)) = 0u;
}

// fused cast+pair: block = one 16-fact tile. Coalesced f32 reads -> fp8 LDS
// tiles; fa1b/fa2b written as contiguous block copies; frel tile consumed
// in-LDS (never hits global). Wave 0 computes all dots/norms via fp8 MFMA.
__global__ __launch_bounds__(256) void k_castpair(
    const float* __restrict__ frel, const float* __restrict__ fa1,
    const float* __restrict__ fa2, const unsigned char* __restrict__ qt,
    const int* __restrict__ nbf, float* __restrict__ lw1, float* __restrict__ lw2,
    float* __restrict__ s0log, float* __restrict__ nf1, float* __restrict__ nf2,
    unsigned char* __restrict__ fa1b, unsigned char* __restrict__ fa2b,
    int B, int F) {
    int ti = blockIdx.x, b = blockIdx.y;
    int f0 = ti * 16;
    int tid = threadIdx.x;
    __shared__ unsigned char sFR[4096], sF1[4096], sF2[4096];
    __shared__ float vals[16][12];
    __shared__ float qn[8];
    // stage: row = tid>>4 (tile col), 16 lanes x float4 = 256B segments
    int row = tid >> 4;
    int cb = (tid & 15) * 4;
    size_t rbase = ((size_t)b * F + f0 + row) * E;
#pragma unroll
    for (int p = 0; p < 4; ++p) {
        int e0 = p * 64 + cb;
        float4 vr = *(const float4*)(frel + rbase + e0);
        float4 v1 = *(const float4*)(fa1 + rbase + e0);
        float4 v2 = *(const float4*)(fa2 + rbase + e0);
        int off = tile_off(e0, row);
        *(unsigned*)&sFR[off] = pack_fp8x4(vr.x, vr.y, vr.z, vr.w);
        *(unsigned*)&sF1[off] = pack_fp8x4(v1.x, v1.y, v1.z, v1.w);
        *(unsigned*)&sF2[off] = pack_fp8x4(v2.x, v2.y, v2.z, v2.w);
    }
    __syncthreads();
    // coalesced tile stores (LDS and global layouts identical)
    size_t tb = ((size_t)b * (F >> 4) + ti) * 4096;
    *(i64x2*)(fa1b + tb + tid * 16) = *(const i64x2*)&sF1[tid * 16];
    *(i64x2*)(fa2b + tb + tid * 16) = *(const i64x2*)&sF2[tid * 16];
    if (tid >= 64) return;  // wave 0 does the MFMA + epilogue
    int lane = tid, lr = lane & 15, lk = lane >> 4;
    const unsigned char* qp = qt + (size_t)b * 4096 + lane * 16;
    long Q[8], FR[8], F1[8], F2[8];
#pragma unroll
    for (int g = 0; g < 4; ++g) {
        i64x2 a = *(const i64x2*)(qp + g * 1024);
        Q[2 * g] = a.x; Q[2 * g + 1] = a.y;
        i64x2 c = *(const i64x2*)&sFR[g * 1024 + lane * 16];
        FR[2 * g] = c.x; FR[2 * g + 1] = c.y;
        i64x2 d = *(const i64x2*)&sF1[g * 1024 + lane * 16];
        F1[2 * g] = d.x; F1[2 * g + 1] = d.y;
        i64x2 e2 = *(const i64x2*)&sF2[g * 1024 + lane * 16];
        F2[2 * g] = e2.x; F2[2 * g + 1] = e2.y;
    }
    f32x4 Dqq = {0.f, 0.f, 0.f, 0.f}, D1 = Dqq, D2 = Dqq, D3 = Dqq, D4 = Dqq,
          D5 = Dqq, D6 = Dqq;
#pragma unroll
    for (int kb = 0; kb < 8; ++kb) {
        Dqq = __builtin_amdgcn_mfma_f32_16x16x32_fp8_fp8(Q[kb], Q[kb], Dqq, 0, 0, 0);
        D1 = __builtin_amdgcn_mfma_f32_16x16x32_fp8_fp8(Q[kb], FR[kb], D1, 0, 0, 0);
        D2 = __builtin_amdgcn_mfma_f32_16x16x32_fp8_fp8(Q[kb], F1[kb], D2, 0, 0, 0);
        D3 = __builtin_amdgcn_mfma_f32_16x16x32_fp8_fp8(Q[kb], F2[kb], D3, 0, 0, 0);
        D4 = __builtin_amdgcn_mfma_f32_16x16x32_fp8_fp8(FR[kb], FR[kb], D4, 0, 0, 0);
        D5 = __builtin_amdgcn_mfma_f32_16x16x32_fp8_fp8(F1[kb], F1[kb], D5, 0, 0, 0);
        D6 = __builtin_amdgcn_mfma_f32_16x16x32_fp8_fp8(F2[kb], F2[kb], D6, 0, 0, 0);
    }
    // scatter needed values (wave-local LDS, same-wave ordering)
#pragma unroll
    for (int j = 0; j < 4; ++j) {
        int q = lk * 4 + j;
        if (q == 0) vals[lr][0] = D1[j];   // rel . fr
        if (q == 3) vals[lr][1] = D1[j];   // h00 . fr
        if (q == 4) vals[lr][2] = D1[j];   // h01 . fr
        if (q == 5) vals[lr][3] = D1[j];   // h10 . fr
        if (q == 6) vals[lr][4] = D1[j];   // h11 . fr
        if (q == 1) { vals[lr][5] = D2[j]; vals[lr][7] = D3[j]; }
        if (q == 2) { vals[lr][6] = D2[j]; vals[lr][8] = D3[j]; }
        if (q == lr) {
            vals[lr][9] = D4[j];   // |fr|^2
            vals[lr][10] = D5[j];  // |f1|^2
            vals[lr][11] = D6[j];  // |f2|^2
            if (q < 7) qn[q] = Dqq[j];
        }
    }
    if (lane < 16) {
        int f = f0 + lane;
        size_t bf = (size_t)b * F + f;
        const float* vv = vals[lane];
        float nfr = vv[9], n1 = vv[10], n2 = vv[11];
        bool msk = (f < nbf[b]);
        float rrel  = fmaxf(qn[0] + nfr - 2.f * vv[0], 0.f);
        float rh00  = fmaxf(qn[3] + nfr - 2.f * vv[1], 0.f);
        float rh01  = fmaxf(qn[4] + nfr - 2.f * vv[2], 0.f);
        float rh10  = fmaxf(qn[5] + nfr - 2.f * vv[3], 0.f);
        float rh11  = fmaxf(qn[6] + nfr - 2.f * vv[4], 0.f);
        float ra1f1 = fmaxf(qn[1] + n1 - 2.f * vv[5], 0.f);
        float ra2f1 = fmaxf(qn[2] + n1 - 2.f * vv[6], 0.f);
        float ra1f2 = fmaxf(qn[1] + n2 - 2.f * vv[7], 0.f);
        float ra2f2 = fmaxf(qn[2] + n2 - 2.f * vv[8], 0.f);
        nf1[bf] = n1;
        nf2[bf] = n2;
        lw1[bf]                 = msk ? -0.5f * (rh00 + ra1f1) : NINF;
        lw1[(size_t)B * F + bf] = msk ? -0.5f * (rh10 + ra1f2) : NINF;
        lw2[bf]                 = msk ? -0.5f * (rh01 + ra2f2) : NINF;
        lw2[(size_t)B * F + bf] = msk ? -0.5f * (rh11 + ra2f1) : NINF;
        s0log[bf] = msk ? -0.5f * (rrel + ra1f1 + ra2f2) : NINF;
    }
}

// out[b] = exp(max_f s0log[b][f])
__global__ void k_s0red(const float* __restrict__ s0log, float* __restrict__ out,
                        int B, int F) {
    int b = blockIdx.x;
    int tid = threadIdx.x, lane = tid & 63, wave = tid >> 6;
    float m = NINF;
    for (int f = tid; f < F; f += 256) m = fmaxf(m, s0log[(size_t)b * F + f]);
    m = wmax(m);
    __shared__ float red[4];
    if (lane == 0) red[wave] = m;
    __syncthreads();
    if (tid == 0) out[b] = expf(fmaxf(fmaxf(red[0], red[1]), fmaxf(red[2], red[3])));
}

// hop1: fp8 MFMA. A (32 rows/wave) in regs from tiled ent; B staged 32 cols
// (8KB) per step to LDS, double-buffered, shared by 4 waves: 8 steps of
// {16 ds_read + 32 MFMA + 1 barrier} (half the barriers of 16-col steps).
// Grid 2048: b(16) x r(2) x nb(8: 128-row) x fs(8: 256-col), XCD-swizzled.
__global__ __launch_bounds__(256, 4) void k_hop1m(
    const unsigned char* __restrict__ entt, const unsigned char* __restrict__ fa1b,
    const unsigned char* __restrict__ fa2b, const float* __restrict__ nf1,
    const float* __restrict__ nf2, const float* __restrict__ ne,
    const float* __restrict__ lw1, float* __restrict__ nsc_part, int B, int N, int F) {
    int L = blockIdx.x;
    int xcd = L & 7, s = L >> 3;
    int b = ((s >> 7) << 3) | xcd;  // batch-pair {xcd, xcd+8} per XCD
    int inner = s & 127;
    int r = inner >> 6, nb = (inner >> 3) & 7, fs = inner & 7;
    int BR = nb * 128;
    int F0 = fs * 256;
    const unsigned char* factb = (r == 0) ? fa2b : fa1b;
    const float* nfp = ((r == 0) ? nf2 : nf1) + (size_t)b * F;
    const float* w = lw1 + ((size_t)r * B + b) * F;
    const float* nep = ne + (size_t)b * N;

    __shared__ unsigned char bT[2][8192];

    int tid = threadIdx.x, lane = tid & 63, wave = tid >> 6;
    int lr = lane & 15, lk = lane >> 4;
    int row0 = BR + wave * 32;

    // A fragments: 2 m-frags x 8 kb; [g][lk][col] layout -> contiguous 16B loads
    const unsigned char* At = entt + (size_t)b * N * E;
    long areg[2][8];
#pragma unroll
    for (int m = 0; m < 2; ++m) {
        const unsigned char* p = At + (size_t)((row0 >> 4) + m) * 4096 + lk * 256 +
                                 lr * 16;
#pragma unroll
        for (int g = 0; g < 4; ++g) {
            i64x2 vv = *(const i64x2*)(p + g * 1024);
            areg[m][2 * g] = vv.x;
            areg[m][2 * g + 1] = vv.y;
        }
    }
    float nh[2][4];
#pragma unroll
    for (int m = 0; m < 2; ++m)
#pragma unroll
        for (int j = 0; j < 4; ++j)
            nh[m][j] = -0.5f * nep[row0 + m * 16 + lk * 4 + j];
    // preload per-col-tile lw / gf (statically indexed; loops fully unrolled)
    float lwa[16], gfa[16];
#pragma unroll
    for (int t = 0; t < 16; ++t) {
        int fcol = F0 + t * 16 + lr;
        lwa[t] = w[fcol];
        gfa[t] = fmaf(-0.5f, nfp[fcol], lwa[t]);
    }
    float vmax[2][4];
#pragma unroll
    for (int m = 0; m < 2; ++m)
#pragma unroll
        for (int j = 0; j < 4; ++j) vmax[m][j] = NINF;

    const unsigned char* Bt = factb + (size_t)b * F * E + (size_t)(F0 >> 4) * 4096;
#define STG(buf, t)                                                              \
    {                                                                            \
        __builtin_amdgcn_global_load_lds(                                        \
            (const __attribute__((address_space(1))) void*)(Bt + (size_t)(t) * 8192 + \
                                                            wave * 1024 + lane * 16),  \
            (__attribute__((address_space(3))) void*)&bT[buf][wave * 1024], 16, 0, 0); \
        __builtin_amdgcn_global_load_lds(                                        \
            (const __attribute__((address_space(1))) void*)(Bt + (size_t)(t) * 8192 + \
                                                            4096 + wave * 1024 +      \
                                                            lane * 16),               \
            (__attribute__((address_space(3))) void*)&bT[buf][4096 + wave * 1024],     \
            16, 0, 0);                                                           \
    }

    STG(0, 0);
    __syncthreads();
#pragma unroll
    for (int t = 0; t < 8; ++t) {
        int cur = t & 1;
        if (t < 7) STG(cur ^ 1, t + 1);
#pragma unroll
        for (int c = 0; c < 2; ++c) {
            long bfr[8];
#pragma unroll
            for (int g = 0; g < 4; ++g) {
                i64x2 vv = *(const i64x2*)&bT[cur][c * 4096 + g * 1024 + lane * 16];
                bfr[2 * g] = vv.x;
                bfr[2 * g + 1] = vv.y;
            }
            f32x4 acc0 = {0.f, 0.f, 0.f, 0.f}, acc1 = {0.f, 0.f, 0.f, 0.f};
#pragma unroll
            for (int kb = 0; kb < 8; ++kb) {
                acc0 = __builtin_amdgcn_mfma_f32_16x16x32_fp8_fp8(areg[0][kb], bfr[kb],
                                                                  acc0, 0, 0, 0);
                acc1 = __builtin_amdgcn_mfma_f32_16x16x32_fp8_fp8(areg[1][kb], bfr[kb],
                                                                  acc1, 0, 0, 0);
            }
            int idx = t * 2 + c;
#pragma unroll
            for (int j = 0; j < 4; ++j) {
                vmax[0][j] =
                    fmaxf(vmax[0][j], fminf(acc0[j] + gfa[idx] + nh[0][j], lwa[idx]));
                vmax[1][j] =
                    fmaxf(vmax[1][j], fminf(acc1[j] + gfa[idx] + nh[1][j], lwa[idx]));
            }
        }
        __syncthreads();
    }
#undef STG

    // reduce over the 16 lr lanes (different f, same rows); direct store
#pragma unroll
    for (int m = 0; m < 2; ++m)
#pragma unroll
        for (int j = 0; j < 4; ++j) {
            float v = vmax[m][j];
            v = fmaxf(v, __shfl_xor(v, 1, 64));
            v = fmaxf(v, __shfl_xor(v, 2, 64));
            v = fmaxf(v, __shfl_xor(v, 4, 64));
            v = fmaxf(v, __shfl_xor(v, 8, 64));
            if (lr == 0) {
                int row = row0 + m * 16 + lk * 4 + j;
                nsc_part[(size_t)fs * (2 * (size_t)B * N) +
                         ((size_t)r * B + b) * N + row] = v;
            }
        }
}

// top-10 per (r,b), 256 threads, register-resident, parallel NY-fold,
// jax.lax.top_k tie-break (lower index wins on equal value)
__global__ __launch_bounds__(256) void k_topk(const float* __restrict__ nsc_part,
                                              float* __restrict__ zval,
                                              int* __restrict__ zidx, int B, int N) {
    int b = blockIdx.x, r = blockIdx.y;
    int tid = threadIdx.x, lane = tid & 63, wave = tid >> 6;
    size_t rbN = ((size_t)r * B + b) * N;
    size_t ystr = 2 * (size_t)B * N;
    // fold NY partials: 8 independent float4 loads, one latency
    const float4* p0 = (const float4*)(nsc_part + rbN) + tid;
    float4 m = *p0;
#pragma unroll
    for (int y = 1; y < NY; ++y) {
        float4 t = *(const float4*)((const float*)p0 + (size_t)y * ystr);
        m.x = fmaxf(m.x, t.x); m.y = fmaxf(m.y, t.y);
        m.z = fmaxf(m.z, t.z); m.w = fmaxf(m.w, t.w);
    }
    float v0 = expf(m.x), v1 = expf(m.y), v2 = expf(m.z), v3 = expf(m.w);
    int base = tid * 4;
    __shared__ float rv[4];
    __shared__ int ri[4];
    for (int t = 0; t < KTOP; ++t) {
        // per-thread best of 4 (strict > keeps lowest index)
        float bv = v0; int bi = base;
        if (v1 > bv) { bv = v1; bi = base + 1; }
        if (v2 > bv) { bv = v2; bi = base + 2; }
        if (v3 > bv) { bv = v3; bi = base + 3; }
        // wave reduce
#pragma unroll
        for (int off = 32; off > 0; off >>= 1) {
            float ov = __shfl_xor(bv, off, 64);
            int oi = __shfl_xor(bi, off, 64);
            if (ov > bv || (ov == bv && oi < bi)) { bv = ov; bi = oi; }
        }
        if (lane == 0) { rv[wave] = bv; ri[wave] = bi; }
        __syncthreads();
        // cross-wave fold, computed redundantly (deterministic)
        float fb = rv[0]; int fi = ri[0];
#pragma unroll
        for (int wv = 1; wv < 4; ++wv) {
            float ov = rv[wv]; int oi = ri[wv];
            if (ov > fb || (ov == fb && oi < fi)) { fb = ov; fi = oi; }
        }
        if (tid == 0) {
            zval[((size_t)r * B + b) * KTOP + t] = fb;
            zidx[((size_t)r * B + b) * KTOP + t] = fi;
        }
        // owner clears its copy (static indexing via predicated writes)
        int off = fi - base;
        v0 = (off == 0) ? -2.f : v0;
        v1 = (off == 1) ? -2.f : v1;
        v2 = (off == 2) ? -2.f : v2;
        v3 = (off == 3) ? -2.f : v3;
        __syncthreads();
    }
}

// hop2 via fp8 MFMA: 10 gathered sources (A via LDS) vs tiled fact cols (B direct).
__global__ __launch_bounds__(256) void k_hop2m(
    const unsigned char* __restrict__ entb, const unsigned char* __restrict__ fa1b,
    const unsigned char* __restrict__ fa2b, const float* __restrict__ nf1,
    const float* __restrict__ nf2, const float* __restrict__ ne,
    const float* __restrict__ lw2, const int* __restrict__ zidx,
    float* __restrict__ h2part, int B, int N, int F) {
    int L = blockIdx.x;
    int xcd = L & 7, s = L >> 3;
    int b = ((s >> 4) << 3) | xcd;
    int inner = s & 15;
    int r = inner >> 3, c = inner & 7;
    const unsigned char* factb = (r == 0) ? fa1b : fa2b;
    const float* nfp = ((r == 0) ? nf1 : nf2) + (size_t)b * F;
    const float* w = lw2 + ((size_t)r * B + b) * F;
    int tid = threadIdx.x, lane = tid & 63, wave = tid >> 6;
    int lr = lane & 15, lk = lane >> 4;
    __shared__ unsigned char aLds[32 * 16 * 8];  // [kchunk32][row16][8B] = 4KB
    __shared__ float snrm[16];
    for (int ci = tid; ci < 512; ci += 256) {
        int row = ci & 15, kc = ci >> 4;
        long vv = 0;
        if (row < KTOP) {
            int idx = zidx[((size_t)r * B + b) * KTOP + row];
            vv = *(const long*)(entb + ((size_t)b * N + idx) * E + kc * 8);
        }
        *(long*)&aLds[(size_t)ci * 8] = vv;
    }
    if (tid < 16) {
        float nv = 0.f;
        if (tid < KTOP) {
            int idx = zidx[((size_t)r * B + b) * KTOP + tid];
            nv = ne[(size_t)b * N + idx];
        }
        snrm[tid] = nv;
    }
    __syncthreads();
    long afr[8];
#pragma unroll
    for (int kb = 0; kb < 8; ++kb)
        afr[kb] = *(const long*)&aLds[((kb * 4 + lk) * 16 + lr) * 8];
    float nhs[4];
#pragma unroll
    for (int j = 0; j < 4; ++j) nhs[j] = -0.5f * snrm[lk * 4 + j];
    int fbase = c * (F >> 3) + wave * (F >> 5);  // wave's 64 cols
    float vmax[4] = {NINF, NINF, NINF, NINF};
    const unsigned char* Bb = factb + (size_t)b * F * E;
#pragma unroll
    for (int n = 0; n < 4; ++n) {
        int fcol = fbase + n * 16;
        const unsigned char* p = Bb + (size_t)(fcol >> 4) * 4096 + lk * 256 + lr * 16;
        long bfr[8];
#pragma unroll
        for (int g = 0; g < 4; ++g) {
            i64x2 vv = *(const i64x2*)(p + g * 1024);
            bfr[2 * g] = vv.x;
            bfr[2 * g + 1] = vv.y;
        }
        f32x4 acc = {0.f, 0.f, 0.f, 0.f};
#pragma unroll
        for (int kb = 0; kb < 8; ++kb)
            acc = __builtin_amdgcn_mfma_f32_16x16x32_fp8_fp8(afr[kb], bfr[kb], acc,
                                                             0, 0, 0);
        float lwf = w[fcol + lr];
        float gf = fmaf(-0.5f, nfp[fcol + lr], lwf);
#pragma unroll
        for (int j = 0; j < 4; ++j)
            vmax[j] = fmaxf(vmax[j], fminf(acc[j] + gf + nhs[j], lwf));
    }
#pragma unroll
    for (int j = 0; j < 4; ++j) {
        float v = vmax[j];
        v = fmaxf(v, __shfl_xor(v, 1, 64));
        v = fmaxf(v, __shfl_xor(v, 2, 64));
        v = fmaxf(v, __shfl_xor(v, 4, 64));
        v = fmaxf(v, __shfl_xor(v, 8, 64));
        int sidx = lk * 4 + j;
        if (lr == 0 && sidx < KTOP)
            h2part[(((size_t)r * B + b) * KTOP + sidx) * 32 + c * 4 + wave] = v;
    }
}

// combine: out[b] = max(out[b], min(exp(max_c h2part), zval))
__global__ void k_hop2c(const float* __restrict__ h2part, const float* __restrict__ zval,
                        float* __restrict__ out, int B) {
    int i = blockIdx.x * 256 + threadIdx.x;
    int n = 2 * B * KTOP;
    if (i < n) {
        int b = (i / KTOP) % B;
        float m = NINF;
#pragma unroll
        for (int c2 = 0; c2 < 32; ++c2) m = fmaxf(m, h2part[(size_t)i * 32 + c2]);
        float sc = fminf(expf(m), zval[i]);
        atomicMaxF(&out[b], sc);
    }
}

// ---------- launcher ----------
extern "C" void kernel_launch(void* const* d_in, const int* in_sizes, int n_in,
                              void* d_out, int out_size, void* d_ws, size_t ws_size,
                              hipStream_t stream) {
    const float* rel = (const float*)d_in[0];
    const float* arg1 = (const float*)d_in[1];
    const float* arg2 = (const float*)d_in[2];
    const float* frel = (const float*)d_in[3];
    const float* fa1 = (const float*)d_in[4];
    const float* fa2 = (const float*)d_in[5];
    const int* nbf = (const int*)d_in[6];
    const float* ent = (const float*)d_in[7];
    const float* W = (const float*)d_in[9];
    const float* bias = (const float*)d_in[10];
    int B = in_sizes[0] / E;
    int F = in_sizes[3] / (B * E);
    int N = in_sizes[7] / (B * E);
    float* out = (float*)d_out;

    float* ws = (float*)d_ws;
    size_t o = 0;
    float* hr = ws + o;   o += (size_t)4 * B * E;
    float* nf1 = ws + o;  o += (size_t)B * F;
    float* nf2 = ws + o;  o += (size_t)B * F;
    float* ne_ = ws + o;  o += (size_t)B * N;
    float* lw1 = ws + o;  o += (size_t)2 * B * F;
    float* lw2 = ws + o;  o += (size_t)2 * B * F;
    float* zval = ws + o; o += (size_t)2 * B * KTOP;
    int* zidx = (int*)(ws + o); o += (size_t)2 * B * KTOP;
    float* s0log = ws + o; o += (size_t)B * F;
    float* h2part = ws + o; o += (size_t)2 * B * KTOP * 32;
    float* nsc_part = ws + o; o += (size_t)NY * 2 * B * N;
    unsigned char* fa1b = (unsigned char*)(ws + o); o += (size_t)B * F * E / 4;
    unsigned char* fa2b = (unsigned char*)(ws + o); o += (size_t)B * F * E / 4;
    unsigned char* entb = (unsigned char*)(ws + o); o += (size_t)B * N * E / 4;
    unsigned char* entt = (unsigned char*)(ws + o); o += (size_t)B * N * E / 4;
    unsigned char* qt = (unsigned char*)(ws + o);   o += (size_t)B * 1024;

    k_hoprel<<<dim3(B, 4), dim3(E), 0, stream>>>(rel, W, bias, hr, B);
    k_prep_ent<<<dim3((B * N + 3) / 4), dim3(256), 0, stream>>>(ent, entb, entt, ne_,
                                                                B * N, N);
    k_prep_q<<<dim3(B), dim3(64), 0, stream>>>(rel, arg1, arg2, hr, qt, B);
    k_castpair<<<dim3(F / 16, B), dim3(256), 0, stream>>>(
        frel, fa1, fa2, qt, nbf, lw1, lw2, s0log, nf1, nf2, fa1b, fa2b, B, F);
    k_s0red<<<dim3(B), dim3(256), 0, stream>>>(s0log, out, B, F);
    k_hop1m<<<dim3(2048), dim3(256), 0, stream>>>(entt, fa1b, fa2b, nf1, nf2, ne_, lw1,
                                                  nsc_part, B, N, F);
    k_topk<<<dim3(B, 2), dim3(256), 0, stream>>>(nsc_part, zval, zidx, B, N);
    k_hop2m<<<dim3(256), dim3(256), 0, stream>>>(entb, fa1b, fa2b, nf1, nf2, ne_, lw2,
                                                 zidx, h2part, B, N, F);
    k_hop2c<<<dim3((2 * B * KTOP + 255) / 256), dim3(256), 0, stream>>>(h2part, zval,
                                                                        out, B);
}